// Round 1
// baseline (3737.482 us; speedup 1.0000x reference)
//
#include <hip/hip_runtime.h>
#include <hip/hip_bf16.h>

typedef unsigned short u16;
typedef unsigned int u32;

__device__ __forceinline__ float bf2f(u16 u){
  union { u32 i; float f; } v; v.i = ((u32)u) << 16; return v.f;
}
__device__ __forceinline__ u16 f2bf(float f){
  union { float f; u32 i; } v; v.f = f;
  u32 r = v.i + 0x7fffu + ((v.i >> 16) & 1u);
  return (u16)(r >> 16);
}
__device__ __forceinline__ void unpack8(uint4 v, float* dst){
  dst[0]=bf2f((u16)(v.x & 0xffff)); dst[1]=bf2f((u16)(v.x >> 16));
  dst[2]=bf2f((u16)(v.y & 0xffff)); dst[3]=bf2f((u16)(v.y >> 16));
  dst[4]=bf2f((u16)(v.z & 0xffff)); dst[5]=bf2f((u16)(v.z >> 16));
  dst[6]=bf2f((u16)(v.w & 0xffff)); dst[7]=bf2f((u16)(v.w >> 16));
}

// ---------------------------------------------------------------------------
// Generic fp32 [rows][cols] -> bf16 [cols][rows] transpose, one image per z.
// Used for x (NCHW->NHWC), xs (NCHW->NHWC), and weights ([co][ci*9]->[ci*9][co]).
__global__ __launch_bounds__(256) void k_transpose(const float* __restrict__ in,
                                                   u16* __restrict__ out,
                                                   int rows, int cols){
  __shared__ float s[32][33];
  size_t img = (size_t)blockIdx.z * (size_t)rows * (size_t)cols;
  const float* ip = in + img;
  u16* op = out + img;
  int r0 = blockIdx.x * 32, c0 = blockIdx.y * 32;
  int tx = threadIdx.x, ty = threadIdx.y;
#pragma unroll
  for(int i = 0; i < 4; ++i){
    int r = ty * 4 + i;
    s[r][tx] = ip[(size_t)(r0 + r) * cols + (c0 + tx)];
  }
  __syncthreads();
#pragma unroll
  for(int i = 0; i < 4; ++i){
    int c = ty * 4 + i;
    op[(size_t)(c0 + c) * rows + (r0 + tx)] = f2bf(s[tx][c]);
  }
}

// ---------------------------------------------------------------------------
// Scores for 8x8 patches. GEMM  S8[b][q=256][k=1280] = sum_d q_patch . k_patch
// K-dim ordered as (dy,dx,c): K-split over (dy,dx) groups (8 groups of 8).
// S8p layout: [g=8][b=2][256][1280] fp32 partials.
__global__ __launch_bounds__(256) void k_scores8(const u16* __restrict__ XT,
                                                 const u16* __restrict__ XST,
                                                 float* __restrict__ S8p){
  __shared__ float As[64][68], Bs[64][68];
  int b = blockIdx.z >> 3, g = blockIdx.z & 7;
  int q0 = blockIdx.x * 64, k0 = blockIdx.y * 64;
  int tid = threadIdx.x;
  int row = tid >> 2, quarter = tid & 3;
  int qg = tid >> 4, kg = tid & 15;
  float acc[4][4] = {{0.f}};
  for(int e8 = 0; e8 < 8; ++e8){
    int e = g * 8 + e8;          // patch-local pixel 0..63
    int dy = e >> 3, dx = e & 7;
    // A row address (per-thread constant parts)
    int q = q0 + row;
    int apy = ((q >> 4) << 3) + dy, apx = ((q & 15) << 3) + dx;
    const u16* abase = XT + (((size_t)b * 128 + apy) * 128 + apx) * 256 + quarter * 16;
    int k = k0 + row;
    int t = k >> 8, rm = k & 255;
    int bpy = ((rm >> 4) << 3) + dy, bpx = ((rm & 15) << 3) + dx;
    const u16* bbase = XST + ((((size_t)b * 5 + t) * 128 + bpy) * 128 + bpx) * 256 + quarter * 16;
    for(int cc = 0; cc < 4; ++cc){
      int c0 = cc * 64;
      {
        const uint4* s4 = (const uint4*)(abase + c0);
        uint4 v0 = s4[0], v1 = s4[1];
        unpack8(v0, &As[row][quarter * 16]);
        unpack8(v1, &As[row][quarter * 16 + 8]);
      }
      {
        const uint4* s4 = (const uint4*)(bbase + c0);
        uint4 v0 = s4[0], v1 = s4[1];
        unpack8(v0, &Bs[row][quarter * 16]);
        unpack8(v1, &Bs[row][quarter * 16 + 8]);
      }
      __syncthreads();
#pragma unroll 8
      for(int kk = 0; kk < 64; ++kk){
        float a[4], bb[4];
#pragma unroll
        for(int i = 0; i < 4; ++i) a[i] = As[qg + 16 * i][kk];
#pragma unroll
        for(int j = 0; j < 4; ++j) bb[j] = Bs[kg + 16 * j][kk];
#pragma unroll
        for(int i = 0; i < 4; ++i)
#pragma unroll
          for(int j = 0; j < 4; ++j) acc[i][j] += a[i] * bb[j];
      }
      __syncthreads();
    }
  }
#pragma unroll
  for(int i = 0; i < 4; ++i){
    int q = q0 + qg + 16 * i;
    float* dst = S8p + (((size_t)g * 2 + b) * 256 + q) * 1280 + k0;
#pragma unroll
    for(int j = 0; j < 4; ++j) dst[kg + 16 * j] = acc[i][j];
  }
}

__global__ __launch_bounds__(256) void k_reduce8(const float* __restrict__ S8p,
                                                 float* __restrict__ S8){
  size_t i = (size_t)blockIdx.x * 256 + threadIdx.x; // 655360 total
  float s = 0.f;
#pragma unroll
  for(int g = 0; g < 8; ++g) s += S8p[(size_t)g * 655360 + i];
  S8[i] = s;
}

// softmax over k (1280) with scale 1/sqrt(16384)=1/128
__global__ __launch_bounds__(256) void k_softmax8(const float* __restrict__ S8,
                                                  float* __restrict__ A8){
  __shared__ float red[8];
  int b = blockIdx.x >> 8, q = blockIdx.x & 255;
  const float* row = S8 + ((size_t)b * 256 + q) * 1280;
  float* orow = A8 + ((size_t)b * 256 + q) * 1280;
  int tid = threadIdx.x;
  float v[5]; float m = -1e30f;
#pragma unroll
  for(int i = 0; i < 5; ++i){ v[i] = row[tid + 256 * i] * 0.0078125f; m = fmaxf(m, v[i]); }
#pragma unroll
  for(int o = 32; o > 0; o >>= 1) m = fmaxf(m, __shfl_xor(m, o));
  int wid = tid >> 6;
  if((tid & 63) == 0) red[wid] = m;
  __syncthreads();
  m = fmaxf(fmaxf(red[0], red[1]), fmaxf(red[2], red[3]));
  float s = 0.f;
#pragma unroll
  for(int i = 0; i < 5; ++i){ v[i] = __expf(v[i] - m); s += v[i]; }
#pragma unroll
  for(int o = 32; o > 0; o >>= 1) s += __shfl_xor(s, o);
  if((tid & 63) == 0) red[4 + wid] = s;
  __syncthreads();
  s = red[4] + red[5] + red[6] + red[7];
  float inv = 1.0f / s;
#pragma unroll
  for(int i = 0; i < 5; ++i) orow[tid + 256 * i] = v[i] * inv;
}

// scores16 via quadrant decomposition of S8, then softmax over 320. scale 1/256.
__global__ __launch_bounds__(320) void k_s16(const float* __restrict__ S8,
                                             float* __restrict__ A16){
  __shared__ float red[10];
  int b = blockIdx.x >> 6, q16 = blockIdx.x & 63;
  int tid = threadIdx.x;               // k16 in 0..319
  int t = tid >> 6, rm = tid & 63;
  int KY = rm >> 3, KX = rm & 7;
  int QY = q16 >> 3, QX = q16 & 7;
  float s = 0.f;
#pragma unroll
  for(int i = 0; i < 2; ++i)
#pragma unroll
    for(int j = 0; j < 2; ++j){
      int q8 = (2 * QY + i) * 16 + (2 * QX + j);
      int k8 = t * 256 + (2 * KY + i) * 16 + (2 * KX + j);
      s += S8[((size_t)b * 256 + q8) * 1280 + k8];
    }
  s *= 0.00390625f; // 1/256
  float m = s;
#pragma unroll
  for(int o = 32; o > 0; o >>= 1) m = fmaxf(m, __shfl_xor(m, o));
  int wid = tid >> 6;
  if((tid & 63) == 0) red[wid] = m;
  __syncthreads();
  m = fmaxf(fmaxf(fmaxf(red[0], red[1]), fmaxf(red[2], red[3])), red[4]);
  float e = __expf(s - m);
  float sm = e;
#pragma unroll
  for(int o = 32; o > 0; o >>= 1) sm += __shfl_xor(sm, o);
  if((tid & 63) == 0) red[5 + wid] = sm;
  __syncthreads();
  sm = red[5] + red[6] + red[7] + red[8] + red[9];
  A16[((size_t)b * 64 + q16) * 320 + tid] = e / sm;
}

// val8: for fixed (b,ry,rx): out[q=256][ch=256] = A8[q][k] * G[k][ch],
// G[k][ch] = XST[b*5+t][KY*8+ry][KX*8+rx][ch].  Writes OUTCAT channels 0..255.
__global__ __launch_bounds__(256) void k_val8(const float* __restrict__ A8,
                                              const u16* __restrict__ XST,
                                              u16* __restrict__ OUTCAT){
  __shared__ float As[64][68], Bs[64][68];
  int z = blockIdx.z; int b = z >> 6, rr = z & 63;
  int ry = rr >> 3, rx = rr & 7;
  int q0 = blockIdx.x * 64, c0 = blockIdx.y * 64;
  int tid = threadIdx.x;
  int row = tid >> 2, quarter = tid & 3;
  int qg = tid >> 4, cg = tid & 15;
  float acc[4][4] = {{0.f}};
  for(int k0 = 0; k0 < 1280; k0 += 64){
    {
      const float* src = A8 + ((size_t)b * 256 + q0 + row) * 1280 + k0 + quarter * 16;
      float4 v0 = ((const float4*)src)[0];
      float4 v1 = ((const float4*)src)[1];
      float4 v2 = ((const float4*)src)[2];
      float4 v3 = ((const float4*)src)[3];
      float4* d = (float4*)&As[row][quarter * 16];
      d[0] = v0; d[1] = v1; d[2] = v2; d[3] = v3;
    }
    {
      int k = k0 + row;
      int t = k >> 8, rm = k & 255;
      int py = ((rm >> 4) << 3) + ry, px = ((rm & 15) << 3) + rx;
      const uint4* s4 = (const uint4*)(XST + ((((size_t)b * 5 + t) * 128 + py) * 128 + px) * 256 + c0 + quarter * 16);
      uint4 v0 = s4[0], v1 = s4[1];
      unpack8(v0, &Bs[row][quarter * 16]);
      unpack8(v1, &Bs[row][quarter * 16 + 8]);
    }
    __syncthreads();
#pragma unroll 8
    for(int kk = 0; kk < 64; ++kk){
      float a[4], bb[4];
#pragma unroll
      for(int i = 0; i < 4; ++i) a[i] = As[qg + 16 * i][kk];
#pragma unroll
      for(int j = 0; j < 4; ++j) bb[j] = Bs[kk][cg + 16 * j];
#pragma unroll
      for(int i = 0; i < 4; ++i)
#pragma unroll
        for(int j = 0; j < 4; ++j) acc[i][j] += a[i] * bb[j];
    }
    __syncthreads();
  }
#pragma unroll
  for(int i = 0; i < 4; ++i){
    int q = q0 + qg + 16 * i;
    int py = ((q >> 4) << 3) + ry, px = ((q & 15) << 3) + rx;
    u16* dst = OUTCAT + (((size_t)b * 128 + py) * 128 + px) * 512 + c0;
#pragma unroll
    for(int j = 0; j < 4; ++j) dst[cg + 16 * j] = f2bf(acc[i][j]);
  }
}

// val16: for fixed (b,ry,rx) in 16x16: out[q=64][ch=256] = A16[q][k] * G16[k][ch].
// Writes OUTCAT channels 256..511.
__global__ __launch_bounds__(256) void k_val16(const float* __restrict__ A16,
                                               const u16* __restrict__ XST,
                                               u16* __restrict__ OUTCAT){
  __shared__ float As[64][68], Bs[64][68];
  int z = blockIdx.z; int b = z >> 8, rr = z & 255;
  int ry = rr >> 4, rx = rr & 15;
  int c0 = blockIdx.y * 64;
  int tid = threadIdx.x;
  int row = tid >> 2, quarter = tid & 3;
  int qg = tid >> 4, cg = tid & 15;
  float acc[4][4] = {{0.f}};
  for(int k0 = 0; k0 < 320; k0 += 64){
    {
      const float* src = A16 + ((size_t)b * 64 + row) * 320 + k0 + quarter * 16;
      float4 v0 = ((const float4*)src)[0];
      float4 v1 = ((const float4*)src)[1];
      float4 v2 = ((const float4*)src)[2];
      float4 v3 = ((const float4*)src)[3];
      float4* d = (float4*)&As[row][quarter * 16];
      d[0] = v0; d[1] = v1; d[2] = v2; d[3] = v3;
    }
    {
      int k = k0 + row;
      int t = k >> 6, rm = k & 63;
      int py = ((rm >> 3) << 4) + ry, px = ((rm & 7) << 4) + rx;
      const uint4* s4 = (const uint4*)(XST + ((((size_t)b * 5 + t) * 128 + py) * 128 + px) * 256 + c0 + quarter * 16);
      uint4 v0 = s4[0], v1 = s4[1];
      unpack8(v0, &Bs[row][quarter * 16]);
      unpack8(v1, &Bs[row][quarter * 16 + 8]);
    }
    __syncthreads();
#pragma unroll 8
    for(int kk = 0; kk < 64; ++kk){
      float a[4], bb[4];
#pragma unroll
      for(int i = 0; i < 4; ++i) a[i] = As[qg + 16 * i][kk];
#pragma unroll
      for(int j = 0; j < 4; ++j) bb[j] = Bs[kk][cg + 16 * j];
#pragma unroll
      for(int i = 0; i < 4; ++i)
#pragma unroll
        for(int j = 0; j < 4; ++j) acc[i][j] += a[i] * bb[j];
    }
    __syncthreads();
  }
#pragma unroll
  for(int i = 0; i < 4; ++i){
    int q = qg + 16 * i;
    int py = ((q >> 3) << 4) + ry, px = ((q & 7) << 4) + rx;
    u16* dst = OUTCAT + (((size_t)b * 128 + py) * 128 + px) * 512 + 256 + c0;
#pragma unroll
    for(int j = 0; j < 4; ++j) dst[cg + 16 * j] = f2bf(acc[i][j]);
  }
}

// conv_lin: LIN[b][pix][co] = leaky( conv3x3(OUTCAT, WTl) + bias ), NHWC GEMM.
__global__ __launch_bounds__(256) void k_conv_lin(const u16* __restrict__ OUTCAT,
                                                  const u16* __restrict__ WT,
                                                  const float* __restrict__ bias,
                                                  u16* __restrict__ LIN){
  __shared__ float As[64][68], Bs[64][68];
  int b = blockIdx.z;
  int pt = blockIdx.x;
  int co0 = blockIdx.y * 64;
  int py0 = (pt >> 4) * 8, px0 = (pt & 15) * 8;
  int tid = threadIdx.x;
  int row = tid >> 2, quarter = tid & 3;
  int qg = tid >> 4, cg = tid & 15;
  float acc[4][4] = {{0.f}};
  for(int e = 0; e < 9; ++e){
    int dy = e / 3 - 1, dx = e % 3 - 1;
    int apy = py0 + (row >> 3) + dy, apx = px0 + (row & 7) + dx;
    bool inb = ((unsigned)apy < 128u) && ((unsigned)apx < 128u);
    const u16* abase = OUTCAT + (((size_t)b * 128 + apy) * 128 + apx) * 512 + quarter * 16;
    for(int cc = 0; cc < 8; ++cc){
      int ci0 = cc * 64;
      if(inb){
        const uint4* s4 = (const uint4*)(abase + ci0);
        uint4 v0 = s4[0], v1 = s4[1];
        unpack8(v0, &As[row][quarter * 16]);
        unpack8(v1, &As[row][quarter * 16 + 8]);
      } else {
#pragma unroll
        for(int s = 0; s < 16; ++s) As[row][quarter * 16 + s] = 0.f;
      }
      {
        const uint4* s4 = (const uint4*)(WT + ((size_t)(ci0 + row) * 9 + e) * 256 + co0 + quarter * 16);
        uint4 v0 = s4[0], v1 = s4[1];
        unpack8(v0, &Bs[row][quarter * 16]);
        unpack8(v1, &Bs[row][quarter * 16 + 8]);
      }
      __syncthreads();
#pragma unroll 8
      for(int kk = 0; kk < 64; ++kk){
        float a[4], bb[4];
#pragma unroll
        for(int i = 0; i < 4; ++i) a[i] = As[qg + 16 * i][kk];
#pragma unroll
        for(int j = 0; j < 4; ++j) bb[j] = Bs[kk][cg + 16 * j];
#pragma unroll
        for(int i = 0; i < 4; ++i)
#pragma unroll
          for(int j = 0; j < 4; ++j) acc[i][j] += a[i] * bb[j];
      }
      __syncthreads();
    }
  }
#pragma unroll
  for(int i = 0; i < 4; ++i){
    int p = qg + 16 * i;
    int py = py0 + (p >> 3), px = px0 + (p & 7);
    u16* dst = LIN + (((size_t)b * 128 + py) * 128 + px) * 256 + co0;
#pragma unroll
    for(int j = 0; j < 4; ++j){
      float v = acc[i][j] + bias[co0 + cg + 16 * j];
      v = v > 0.f ? v : 0.2f * v;
      dst[cg + 16 * j] = f2bf(v);
    }
  }
}

// Fused gating+feature convs over fused=concat(x, LIN); writes d_out NCHW fp32.
__global__ __launch_bounds__(256) void k_final(const u16* __restrict__ XT,
                                               const u16* __restrict__ LIN,
                                               const u16* __restrict__ WTg,
                                               const u16* __restrict__ WTf,
                                               const float* __restrict__ bg,
                                               const float* __restrict__ bf,
                                               float* __restrict__ out){
  __shared__ float As[64][68], Bg[64][68], Bf[64][68];
  int b = blockIdx.z;
  int pt = blockIdx.x;
  int co0 = blockIdx.y * 64;
  int py0 = (pt >> 4) * 8, px0 = (pt & 15) * 8;
  int tid = threadIdx.x;
  int row = tid >> 2, quarter = tid & 3;
  int qg = tid >> 4, cg = tid & 15;
  float accg[4][4] = {{0.f}}, accf[4][4] = {{0.f}};
  for(int e = 0; e < 9; ++e){
    int dy = e / 3 - 1, dx = e % 3 - 1;
    int apy = py0 + (row >> 3) + dy, apx = px0 + (row & 7) + dx;
    bool inb = ((unsigned)apy < 128u) && ((unsigned)apx < 128u);
    size_t pixoff = (((size_t)b * 128 + apy) * 128 + apx) * 256;
    for(int cc = 0; cc < 8; ++cc){
      int ci0 = cc * 64;
      const u16* asrc = (ci0 < 256 ? XT + pixoff + ci0 : LIN + pixoff + (ci0 - 256)) + quarter * 16;
      if(inb){
        uint4 v0 = ((const uint4*)asrc)[0], v1 = ((const uint4*)asrc)[1];
        unpack8(v0, &As[row][quarter * 16]);
        unpack8(v1, &As[row][quarter * 16 + 8]);
      } else {
#pragma unroll
        for(int s = 0; s < 16; ++s) As[row][quarter * 16 + s] = 0.f;
      }
      size_t woff = ((size_t)(ci0 + row) * 9 + e) * 256 + co0 + quarter * 16;
      {
        uint4 v0 = ((const uint4*)(WTg + woff))[0], v1 = ((const uint4*)(WTg + woff))[1];
        unpack8(v0, &Bg[row][quarter * 16]);
        unpack8(v1, &Bg[row][quarter * 16 + 8]);
      }
      {
        uint4 v0 = ((const uint4*)(WTf + woff))[0], v1 = ((const uint4*)(WTf + woff))[1];
        unpack8(v0, &Bf[row][quarter * 16]);
        unpack8(v1, &Bf[row][quarter * 16 + 8]);
      }
      __syncthreads();
#pragma unroll 4
      for(int kk = 0; kk < 64; ++kk){
        float a[4], g4[4], f4[4];
#pragma unroll
        for(int i = 0; i < 4; ++i) a[i] = As[qg + 16 * i][kk];
#pragma unroll
        for(int j = 0; j < 4; ++j){ g4[j] = Bg[kk][cg + 16 * j]; f4[j] = Bf[kk][cg + 16 * j]; }
#pragma unroll
        for(int i = 0; i < 4; ++i)
#pragma unroll
          for(int j = 0; j < 4; ++j){
            accg[i][j] += a[i] * g4[j];
            accf[i][j] += a[i] * f4[j];
          }
      }
      __syncthreads();
    }
  }
#pragma unroll
  for(int i = 0; i < 4; ++i){
    int p = qg + 16 * i;
    int py = py0 + (p >> 3), px = px0 + (p & 7);
#pragma unroll
    for(int j = 0; j < 4; ++j){
      int co = co0 + cg + 16 * j;
      float g = accg[i][j] + bg[co];
      float f = accf[i][j] + bf[co];
      f = f > 0.f ? f : 0.2f * f;
      float r = f / (1.0f + __expf(-g));
      out[(((size_t)b * 256 + co) * 128 + py) * 128 + px] = r;
    }
  }
}

// ---------------------------------------------------------------------------
extern "C" void kernel_launch(void* const* d_in, const int* in_sizes, int n_in,
                              void* d_out, int out_size, void* d_ws, size_t ws_size,
                              hipStream_t stream){
  const float* x      = (const float*)d_in[0];
  const float* xs     = (const float*)d_in[1];
  // d_in[2] = ms : unused (mask is a no-op in the reference)
  const float* w_lin  = (const float*)d_in[3];
  const float* b_lin  = (const float*)d_in[4];
  const float* w_gate = (const float*)d_in[5];
  const float* b_gate = (const float*)d_in[6];
  const float* w_feat = (const float*)d_in[7];
  const float* b_feat = (const float*)d_in[8];
  float* out = (float*)d_out;

  char* ws = (char*)d_ws;
  size_t off = 0;
  auto alloc = [&](size_t bytes) -> void* {
    void* p = ws + off;
    off += (bytes + 255) & ~(size_t)255;
    return p;
  };
  u16* XT     = (u16*)alloc(8388608ull * 2);    // x  NHWC bf16 [2][128][128][256]
  u16* XST    = (u16*)alloc(41943040ull * 2);   // xs NHWC bf16 [10][128][128][256]
  u16* WTl    = (u16*)alloc(1179648ull * 2);    // [ci*9][co] bf16
  u16* WTg    = (u16*)alloc(1179648ull * 2);
  u16* WTf    = (u16*)alloc(1179648ull * 2);
  float* S8p  = (float*)alloc(8ull * 655360 * 4);
  float* S8   = (float*)alloc(655360ull * 4);
  float* A8   = (float*)alloc(655360ull * 4);
  float* A16  = (float*)alloc(2ull * 64 * 320 * 4);
  u16* OUTCAT = (u16*)alloc(2ull * 128 * 128 * 512 * 2); // [b][pix][512] bf16
  u16* LIN    = (u16*)alloc(2ull * 128 * 128 * 256 * 2); // [b][pix][256] bf16

  dim3 tb(32, 8);
  k_transpose<<<dim3(8, 512, 2),  tb, 0, stream>>>(x,      XT,  256, 16384);
  k_transpose<<<dim3(8, 512, 10), tb, 0, stream>>>(xs,     XST, 256, 16384);
  k_transpose<<<dim3(8, 144, 1),  tb, 0, stream>>>(w_lin,  WTl, 256, 4608);
  k_transpose<<<dim3(8, 144, 1),  tb, 0, stream>>>(w_gate, WTg, 256, 4608);
  k_transpose<<<dim3(8, 144, 1),  tb, 0, stream>>>(w_feat, WTf, 256, 4608);

  k_scores8<<<dim3(4, 20, 16), 256, 0, stream>>>(XT, XST, S8p);
  k_reduce8<<<2560, 256, 0, stream>>>(S8p, S8);
  k_softmax8<<<512, 256, 0, stream>>>(S8, A8);
  k_s16<<<128, 320, 0, stream>>>(S8, A16);

  k_val8 <<<dim3(4, 4, 128), 256, 0, stream>>>(A8,  XST, OUTCAT);
  k_val16<<<dim3(1, 4, 512), 256, 0, stream>>>(A16, XST, OUTCAT);

  k_conv_lin<<<dim3(256, 4, 2), 256, 0, stream>>>(OUTCAT, WTl, b_lin, LIN);
  k_final<<<dim3(256, 4, 2), 256, 0, stream>>>(XT, LIN, WTg, WTf, b_gate, b_feat, out);
}

// Round 2
// 575.173 us; speedup vs baseline: 6.4980x; 6.4980x over previous
//
#include <hip/hip_runtime.h>

typedef unsigned short u16;
typedef unsigned int u32;
typedef __attribute__((ext_vector_type(8))) short bf16x8;   // 8 bf16 = 4 VGPR
typedef __attribute__((ext_vector_type(4))) float f32x4;

__device__ __forceinline__ float bf2f(u16 u){
  union { u32 i; float f; } v; v.i = ((u32)u) << 16; return v.f;
}
__device__ __forceinline__ u16 f2bf(float f){
  union { float f; u32 i; } v; v.f = f;
  u32 r = v.i + 0x7fffu + ((v.i >> 16) & 1u);
  return (u16)(r >> 16);
}
__device__ __forceinline__ void unpack8(uint4 v, float* dst){
  dst[0]=bf2f((u16)(v.x & 0xffff)); dst[1]=bf2f((u16)(v.x >> 16));
  dst[2]=bf2f((u16)(v.y & 0xffff)); dst[3]=bf2f((u16)(v.y >> 16));
  dst[4]=bf2f((u16)(v.z & 0xffff)); dst[5]=bf2f((u16)(v.z >> 16));
  dst[6]=bf2f((u16)(v.w & 0xffff)); dst[7]=bf2f((u16)(v.w >> 16));
}

// async global->LDS, 16B per lane; LDS dest = wave-uniform base + lane*16
__device__ __forceinline__ void gl16(const u16* g, u16* l){
  __builtin_amdgcn_global_load_lds(
      (const __attribute__((address_space(1))) u32*)g,
      (__attribute__((address_space(3))) u32*)l, 16, 0, 0);
}

// ---------------------------------------------------------------------------
__global__ __launch_bounds__(64) void k_zero(u32* zp){
  zp[threadIdx.x] = 0u;
}

// fp32 [rows][cols] -> bf16 [cols][rows(+ostride layout)] transpose per image z
__global__ __launch_bounds__(256) void k_transpose(const float* __restrict__ in,
                                                   u16* __restrict__ out,
                                                   int rows, int cols,
                                                   int ostride, size_t o_imgstride){
  __shared__ float s[32][33];
  const float* ip = in + (size_t)blockIdx.z * (size_t)rows * (size_t)cols;
  u16* op = out + (size_t)blockIdx.z * o_imgstride;
  int r0 = blockIdx.x * 32, c0 = blockIdx.y * 32;
  int tx = threadIdx.x, ty = threadIdx.y;
#pragma unroll
  for(int i = 0; i < 4; ++i){
    int r = ty * 4 + i;
    s[r][tx] = ip[(size_t)(r0 + r) * cols + (c0 + tx)];
  }
  __syncthreads();
#pragma unroll
  for(int i = 0; i < 4; ++i){
    int c = ty * 4 + i;
    op[(size_t)(c0 + c) * ostride + (r0 + tx)] = f2bf(s[tx][c]);
  }
}

// weights: [co][ci][3][3] f32 -> [e][co*co_mul+co_off][ci] bf16
__global__ __launch_bounds__(256) void k_wt(const float* __restrict__ in,
                                            u16* __restrict__ out,
                                            int co_mul, int co_off, int co_tot){
  int ci = blockIdx.x * 256 + threadIdx.x;   // 0..511
  int co = blockIdx.y;                       // 0..255
  int e  = blockIdx.z;                       // 0..8
  out[((size_t)e * co_tot + co * co_mul + co_off) * 512 + ci] =
      f2bf(in[((size_t)co * 512 + ci) * 9 + e]);
}

// ---------------------------------------------------------------------------
// scores8 MFMA: S8p[g][b][q=256][k=1280] partials, K-split over 8 tap-groups.
__global__ __launch_bounds__(256) void k_scores8(const u16* __restrict__ FUSED,
                                                 const u16* __restrict__ XST,
                                                 float* __restrict__ S8p){
  __shared__ u16 As[4096], Bs[4096];
  const int bz = blockIdx.z, b = bz >> 3, g = bz & 7;
  const int q0 = blockIdx.x * 128, k0 = blockIdx.y * 128;
  const int tid = threadIdx.x, w = tid >> 6, l = tid & 63;
  const int wr = w >> 1, wc = w & 1;
  const int l15 = l & 15, kg = (l >> 4) * 8;
  f32x4 acc[4][4];
#pragma unroll
  for(int m = 0; m < 4; ++m)
#pragma unroll
    for(int n = 0; n < 4; ++n) acc[m][n] = (f32x4){0.f, 0.f, 0.f, 0.f};

  for(int e8 = 0; e8 < 8; ++e8){
    const int e = g * 8 + e8, dy = e >> 3, dx = e & 7;
    for(int ci0 = 0; ci0 < 256; ci0 += 32){
#pragma unroll
      for(int r = 0; r < 2; ++r){
        const int idx = (w * 2 + r) * 64 + l;
        const int q = q0 + (idx >> 2);
        const size_t pa = ((size_t)b * 16384 +
                           (size_t)(((q >> 4) << 3) + dy) * 128 + ((q & 15) << 3) + dx) * 512
                          + ci0 + (idx & 3) * 8;
        gl16(FUSED + pa, As + (size_t)(w * 2 + r) * 512);
        const int k = k0 + (idx >> 2), t = k >> 8, rm = k & 255;
        const size_t pb = (((size_t)b * 5 + t) * 16384 +
                           (size_t)(((rm >> 4) << 3) + dy) * 128 + ((rm & 15) << 3) + dx) * 256
                          + ci0 + (idx & 3) * 8;
        gl16(XST + pb, Bs + (size_t)(w * 2 + r) * 512);
      }
      __syncthreads();
      bf16x8 af[4], bq[4];
#pragma unroll
      for(int m = 0; m < 4; ++m) af[m] = *(const bf16x8*)(As + (wr * 64 + m * 16 + l15) * 32 + kg);
#pragma unroll
      for(int n = 0; n < 4; ++n) bq[n] = *(const bf16x8*)(Bs + (wc * 64 + n * 16 + l15) * 32 + kg);
#pragma unroll
      for(int m = 0; m < 4; ++m)
#pragma unroll
        for(int n = 0; n < 4; ++n)
          acc[m][n] = __builtin_amdgcn_mfma_f32_16x16x32_bf16(af[m], bq[n], acc[m][n], 0, 0, 0);
      __syncthreads();
    }
  }
  float* dst = S8p + ((size_t)g * 2 + b) * 256 * 1280;
#pragma unroll
  for(int m = 0; m < 4; ++m){
    const int q = q0 + wr * 64 + m * 16 + (l >> 4) * 4;
#pragma unroll
    for(int n = 0; n < 4; ++n){
      const int k = k0 + wc * 64 + n * 16 + l15;
#pragma unroll
      for(int r = 0; r < 4; ++r) dst[(size_t)(q + r) * 1280 + k] = acc[m][n][r];
    }
  }
}

// softmax over k(1280), scale 1/128; sums 8 partials; writes A8 bf16.
__global__ __launch_bounds__(256) void k_softmax8(const float* __restrict__ S8p,
                                                  u16* __restrict__ A8){
  __shared__ float red[8];
  int b = blockIdx.x >> 8, q = blockIdx.x & 255;
  size_t roff = ((size_t)b * 256 + q) * 1280;
  int tid = threadIdx.x;
  float v[5]; float m = -1e30f;
#pragma unroll
  for(int i = 0; i < 5; ++i){
    size_t o = roff + tid + 256 * i;
    float s = 0.f;
#pragma unroll
    for(int g = 0; g < 8; ++g) s += S8p[(size_t)g * 655360 + o];
    v[i] = s * 0.0078125f; m = fmaxf(m, v[i]);
  }
#pragma unroll
  for(int o = 32; o > 0; o >>= 1) m = fmaxf(m, __shfl_xor(m, o));
  int wid = tid >> 6;
  if((tid & 63) == 0) red[wid] = m;
  __syncthreads();
  m = fmaxf(fmaxf(red[0], red[1]), fmaxf(red[2], red[3]));
  float s = 0.f;
#pragma unroll
  for(int i = 0; i < 5; ++i){ v[i] = __expf(v[i] - m); s += v[i]; }
#pragma unroll
  for(int o = 32; o > 0; o >>= 1) s += __shfl_xor(s, o);
  if((tid & 63) == 0) red[4 + wid] = s;
  __syncthreads();
  s = red[4] + red[5] + red[6] + red[7];
  float inv = 1.0f / s;
#pragma unroll
  for(int i = 0; i < 5; ++i) A8[roff + tid + 256 * i] = f2bf(v[i] * inv);
}

// scores16 from S8p quadrants, softmax over 320, scale 1/256 -> A16 f32.
__global__ __launch_bounds__(320) void k_s16(const float* __restrict__ S8p,
                                             float* __restrict__ A16){
  __shared__ float red[10];
  int b = blockIdx.x >> 6, q16 = blockIdx.x & 63;
  int tid = threadIdx.x;               // k16 in 0..319
  int t = tid >> 6, rm = tid & 63;
  int KY = rm >> 3, KX = rm & 7;
  int QY = q16 >> 3, QX = q16 & 7;
  float s = 0.f;
#pragma unroll
  for(int i = 0; i < 2; ++i)
#pragma unroll
    for(int j = 0; j < 2; ++j){
      int q8 = (2 * QY + i) * 16 + (2 * QX + j);
      int k8 = t * 256 + (2 * KY + i) * 16 + (2 * KX + j);
      size_t o = ((size_t)b * 256 + q8) * 1280 + k8;
#pragma unroll
      for(int g = 0; g < 8; ++g) s += S8p[(size_t)g * 655360 + o];
    }
  s *= 0.00390625f; // 1/256
  float m = s;
#pragma unroll
  for(int o = 32; o > 0; o >>= 1) m = fmaxf(m, __shfl_xor(m, o));
  int wid = tid >> 6;
  if((tid & 63) == 0) red[wid] = m;
  __syncthreads();
  m = fmaxf(fmaxf(fmaxf(red[0], red[1]), fmaxf(red[2], red[3])), red[4]);
  float e = __expf(s - m);
  float sm = e;
#pragma unroll
  for(int o = 32; o > 0; o >>= 1) sm += __shfl_xor(sm, o);
  if((tid & 63) == 0) red[5 + wid] = sm;
  __syncthreads();
  sm = red[5] + red[6] + red[7] + red[8] + red[9];
  A16[((size_t)b * 64 + q16) * 320 + tid] = e / sm;
}

// ---------------------------------------------------------------------------
// val8 MFMA: per (b,ry,rx): OUT[q=256][ch=256] = A8[q][1280] @ Gt[ch][1280].
// B staged via in-LDS transpose (NHWC [k][ch] -> LDS [ch][k], swizzled).
__global__ __launch_bounds__(256) void k_val8(const u16* __restrict__ A8,
                                              const u16* __restrict__ XST,
                                              u16* __restrict__ OUTCAT){
  __shared__ u16 As[4096];
  __shared__ u16 Bs[128 * 40];
  const int z = blockIdx.z, b = z >> 6, rr = z & 63;
  const int ry = rr >> 3, rx = rr & 7;
  const int q0 = blockIdx.x * 128, c0 = blockIdx.y * 128;
  const int tid = threadIdx.x, w = tid >> 6, l = tid & 63;
  const int wr = w >> 1, wc = w & 1;
  const int l15 = l & 15, kg = (l >> 4) * 8;
  const int k2 = tid >> 4, ch8 = tid & 15;   // B staging chunk
  f32x4 acc[4][4];
#pragma unroll
  for(int m = 0; m < 4; ++m)
#pragma unroll
    for(int n = 0; n < 4; ++n) acc[m][n] = (f32x4){0.f, 0.f, 0.f, 0.f};

  for(int k0 = 0; k0 < 1280; k0 += 32){
#pragma unroll
    for(int r = 0; r < 2; ++r){
      const int idx = (w * 2 + r) * 64 + l;
      const u16* ga = A8 + ((size_t)b * 256 + q0 + (idx >> 2)) * 1280 + k0 + (idx & 3) * 8;
      gl16(ga, As + (size_t)(w * 2 + r) * 512);
    }
    // B: rows k0+k2*2, k0+k2*2+1, channels c0 + ch8*8 .. +8
    {
      const int ka = k0 + k2 * 2, kb = ka + 1;
      const int ta = ka >> 8, ra = ka & 255;
      const int tb = kb >> 8, rb = kb & 255;
      const size_t pa = (((size_t)b * 5 + ta) * 16384 +
                         (size_t)(((ra >> 4) << 3) + ry) * 128 + ((ra & 15) << 3) + rx) * 256
                        + c0 + ch8 * 8;
      const size_t pb = (((size_t)b * 5 + tb) * 16384 +
                         (size_t)(((rb >> 4) << 3) + ry) * 128 + ((rb & 15) << 3) + rx) * 256
                        + c0 + ch8 * 8;
      union { uint4 v; u16 s[8]; } u0, u1;
      u0.v = *(const uint4*)(XST + pa);
      u1.v = *(const uint4*)(XST + pb);
      const int kloc = k2 * 2, swz = (ch8 & 3) << 3;
#pragma unroll
      for(int j = 0; j < 8; ++j){
        u32 pack = (u32)u0.s[j] | ((u32)u1.s[j] << 16);
        *(u32*)(Bs + (size_t)(ch8 * 8 + j) * 40 + (kloc ^ swz)) = pack;
      }
    }
    __syncthreads();
    bf16x8 af[4], bq[4];
#pragma unroll
    for(int m = 0; m < 4; ++m) af[m] = *(const bf16x8*)(As + (wr * 64 + m * 16 + l15) * 32 + kg);
#pragma unroll
    for(int n = 0; n < 4; ++n){
      const int ch = wc * 64 + n * 16 + l15;
      bq[n] = *(const bf16x8*)(Bs + (size_t)ch * 40 + (kg ^ (((ch >> 3) & 3) << 3)));
    }
#pragma unroll
    for(int m = 0; m < 4; ++m)
#pragma unroll
      for(int n = 0; n < 4; ++n)
        acc[m][n] = __builtin_amdgcn_mfma_f32_16x16x32_bf16(af[m], bq[n], acc[m][n], 0, 0, 0);
    __syncthreads();
  }
#pragma unroll
  for(int m = 0; m < 4; ++m){
    const int qb = q0 + wr * 64 + m * 16 + (l >> 4) * 4;
#pragma unroll
    for(int n = 0; n < 4; ++n){
      const int ch = c0 + wc * 64 + n * 16 + l15;
#pragma unroll
      for(int r = 0; r < 4; ++r){
        const int q = qb + r;
        const int py = ((q >> 4) << 3) + ry, px = ((q & 15) << 3) + rx;
        OUTCAT[((size_t)b * 16384 + (size_t)py * 128 + px) * 512 + ch] = f2bf(acc[m][n][r]);
      }
    }
  }
}

// val16 (fp32 path, small): OUT[q=64][ch=256] per (b,ry16,rx16) -> OUTCAT ch 256..511
__global__ __launch_bounds__(256) void k_val16(const float* __restrict__ A16,
                                               const u16* __restrict__ XST,
                                               u16* __restrict__ OUTCAT){
  __shared__ float As[64][68], Bs[64][68];
  int z = blockIdx.z; int b = z >> 8, rr = z & 255;
  int ry = rr >> 4, rx = rr & 15;
  int c0 = blockIdx.y * 64;
  int tid = threadIdx.x;
  int row = tid >> 2, quarter = tid & 3;
  int qg = tid >> 4, cg = tid & 15;
  float acc[4][4] = {{0.f}};
  for(int k0 = 0; k0 < 320; k0 += 64){
    {
      const float* src = A16 + ((size_t)b * 64 + row) * 320 + k0 + quarter * 16;
      float4 v0 = ((const float4*)src)[0];
      float4 v1 = ((const float4*)src)[1];
      float4 v2 = ((const float4*)src)[2];
      float4 v3 = ((const float4*)src)[3];
      float4* d = (float4*)&As[row][quarter * 16];
      d[0] = v0; d[1] = v1; d[2] = v2; d[3] = v3;
    }
    {
      int k = k0 + row;
      int t = k >> 6, rm = k & 63;
      int py = ((rm >> 3) << 4) + ry, px = ((rm & 7) << 4) + rx;
      const uint4* s4 = (const uint4*)(XST + ((((size_t)b * 5 + t) * 128 + py) * 128 + px) * 256 + c0 + quarter * 16);
      uint4 v0 = s4[0], v1 = s4[1];
      unpack8(v0, &Bs[row][quarter * 16]);
      unpack8(v1, &Bs[row][quarter * 16 + 8]);
    }
    __syncthreads();
#pragma unroll 8
    for(int kk = 0; kk < 64; ++kk){
      float a[4], bb[4];
#pragma unroll
      for(int i = 0; i < 4; ++i) a[i] = As[qg + 16 * i][kk];
#pragma unroll
      for(int j = 0; j < 4; ++j) bb[j] = Bs[kk][cg + 16 * j];
#pragma unroll
      for(int i = 0; i < 4; ++i)
#pragma unroll
        for(int j = 0; j < 4; ++j) acc[i][j] += a[i] * bb[j];
    }
    __syncthreads();
  }
#pragma unroll
  for(int i = 0; i < 4; ++i){
    int q = qg + 16 * i;
    int py = ((q >> 3) << 4) + ry, px = ((q & 7) << 4) + rx;
    u16* dst = OUTCAT + (((size_t)b * 128 + py) * 128 + px) * 512 + 256 + c0;
#pragma unroll
    for(int j = 0; j < 4; ++j) dst[cg + 16 * j] = f2bf(acc[i][j]);
  }
}

// ---------------------------------------------------------------------------
// Conv implicit-GEMM (3x3 SAME, ci=512). MODE 0: +bias, leaky, bf16 ->
// FUSED ch 256..511. MODE 1: interleaved gate/feat pairs, sigmoid(g)*leaky(f)
// -> d_out NCHW f32.
template<int MODE>
__global__ __launch_bounds__(256) void k_conv(const u16* __restrict__ A,
                                              const u16* __restrict__ W,
                                              const float* __restrict__ bias,
                                              const float* __restrict__ bias2,
                                              void* __restrict__ outp,
                                              const u16* __restrict__ zp,
                                              int Ntot){
  __shared__ u16 As[4096], Bs[4096];
  const int py = blockIdx.x, b = blockIdx.z, c0 = blockIdx.y * 128;
  const int tid = threadIdx.x, w = tid >> 6, l = tid & 63;
  const int wr = w >> 1, wc = w & 1;
  const int l15 = l & 15, kg = (l >> 4) * 8;
  f32x4 acc[4][4];
#pragma unroll
  for(int m = 0; m < 4; ++m)
#pragma unroll
    for(int n = 0; n < 4; ++n) acc[m][n] = (f32x4){0.f, 0.f, 0.f, 0.f};

  for(int e = 0; e < 9; ++e){
    const int dy = e / 3 - 1, dx = e % 3 - 1;
    const int arow = py + dy;
    const bool rin = (unsigned)arow < 128u;
    for(int ci0 = 0; ci0 < 512; ci0 += 32){
#pragma unroll
      for(int r = 0; r < 2; ++r){
        const int idx = (w * 2 + r) * 64 + l;
        const int px = (idx >> 2) + dx;
        const bool inb = rin && ((unsigned)px < 128u);
        const u16* ga = inb ? (A + (((size_t)b * 16384 + (size_t)arow * 128 + px) * 512
                                    + ci0 + (idx & 3) * 8))
                            : zp;
        gl16(ga, As + (size_t)(w * 2 + r) * 512);
        const int co = c0 + (idx >> 2);
        const u16* gb = W + (((size_t)e * Ntot + co) * 512 + ci0 + (idx & 3) * 8);
        gl16(gb, Bs + (size_t)(w * 2 + r) * 512);
      }
      __syncthreads();
      bf16x8 af[4], bq[4];
#pragma unroll
      for(int m = 0; m < 4; ++m) af[m] = *(const bf16x8*)(As + (wr * 64 + m * 16 + l15) * 32 + kg);
#pragma unroll
      for(int n = 0; n < 4; ++n) bq[n] = *(const bf16x8*)(Bs + (wc * 64 + n * 16 + l15) * 32 + kg);
#pragma unroll
      for(int m = 0; m < 4; ++m)
#pragma unroll
        for(int n = 0; n < 4; ++n)
          acc[m][n] = __builtin_amdgcn_mfma_f32_16x16x32_bf16(af[m], bq[n], acc[m][n], 0, 0, 0);
      __syncthreads();
    }
  }

  if(MODE == 0){
    u16* ob = (u16*)outp;
#pragma unroll
    for(int m = 0; m < 4; ++m){
      const int p0 = wr * 64 + m * 16 + (l >> 4) * 4;
#pragma unroll
      for(int n = 0; n < 4; ++n){
        const int co = c0 + wc * 64 + n * 16 + l15;
        const float bi = bias[co];
#pragma unroll
        for(int r = 0; r < 4; ++r){
          float v = acc[m][n][r] + bi;
          v = v > 0.f ? v : 0.2f * v;
          ob[((size_t)b * 16384 + (size_t)py * 128 + p0 + r) * 512 + 256 + co] = f2bf(v);
        }
      }
    }
  } else {
    float* ob = (float*)outp;
#pragma unroll
    for(int m = 0; m < 4; ++m){
      const int p0 = wr * 64 + m * 16 + (l >> 4) * 4;
#pragma unroll
      for(int n = 0; n < 4; ++n){
        const int col = c0 + wc * 64 + n * 16 + l15;
        const int s = col & 1, co = col >> 1;
        const float big = bias[co], bif = bias2[co];
        float res[4];
#pragma unroll
        for(int r = 0; r < 4; ++r){
          const float val = acc[m][n][r];
          const float oth = __shfl_xor(val, 1);
          float gg = s ? oth : val;
          float ff = s ? val : oth;
          gg += big; ff += bif;
          ff = ff > 0.f ? ff : 0.2f * ff;
          res[r] = ff / (1.0f + __expf(-gg));
        }
        if(s == 0){
          float4 v4 = make_float4(res[0], res[1], res[2], res[3]);
          *(float4*)&ob[((size_t)b * 256 + co) * 16384 + (size_t)py * 128 + p0] = v4;
        }
      }
    }
  }
}

// ---------------------------------------------------------------------------
extern "C" void kernel_launch(void* const* d_in, const int* in_sizes, int n_in,
                              void* d_out, int out_size, void* d_ws, size_t ws_size,
                              hipStream_t stream){
  const float* x      = (const float*)d_in[0];
  const float* xs     = (const float*)d_in[1];
  // d_in[2] = ms : unused (mask is a no-op in the reference)
  const float* w_lin  = (const float*)d_in[3];
  const float* b_lin  = (const float*)d_in[4];
  const float* w_gate = (const float*)d_in[5];
  const float* b_gate = (const float*)d_in[6];
  const float* w_feat = (const float*)d_in[7];
  const float* b_feat = (const float*)d_in[8];
  float* out = (float*)d_out;

  char* ws = (char*)d_ws;
  size_t off = 0;
  auto alloc = [&](size_t bytes) -> void* {
    void* p = ws + off;
    off += (bytes + 255) & ~(size_t)255;
    return p;
  };
  u16* FUSED  = (u16*)alloc(2ull * 16384 * 512 * 2);  // [b][pix][512]: ch0-255=x, 256-511=lin
  u16* XST    = (u16*)alloc(10ull * 16384 * 256 * 2); // xs NHWC bf16
  u16* WTl    = (u16*)alloc(9ull * 256 * 512 * 2);    // [e][co][ci]
  u16* WGF    = (u16*)alloc(9ull * 512 * 512 * 2);    // [e][2co+s][ci]
  float* S8p  = (float*)alloc(8ull * 655360 * 4);     // [g][b][256][1280]
  u16* A8     = (u16*)alloc(655360ull * 2);           // bf16 [b][256][1280]
  float* A16  = (float*)alloc(2ull * 64 * 320 * 4);
  u16* OUTCAT = (u16*)alloc(2ull * 16384 * 512 * 2);  // [b][pix][512]
  u16* ZP     = (u16*)alloc(256);

  k_zero<<<1, 64, 0, stream>>>((u32*)ZP);

  dim3 tb(32, 8);
  k_transpose<<<dim3(8, 512, 2),  tb, 0, stream>>>(x,  FUSED, 256, 16384, 512, 8388608ull);
  k_transpose<<<dim3(8, 512, 10), tb, 0, stream>>>(xs, XST,   256, 16384, 256, 4194304ull);

  k_wt<<<dim3(2, 256, 9), 256, 0, stream>>>(w_lin,  WTl, 1, 0, 256);
  k_wt<<<dim3(2, 256, 9), 256, 0, stream>>>(w_gate, WGF, 2, 0, 512);
  k_wt<<<dim3(2, 256, 9), 256, 0, stream>>>(w_feat, WGF, 2, 1, 512);

  k_scores8<<<dim3(2, 10, 16), 256, 0, stream>>>(FUSED, XST, S8p);
  k_softmax8<<<512, 256, 0, stream>>>(S8p, A8);
  k_s16<<<128, 320, 0, stream>>>(S8p, A16);

  k_val8 <<<dim3(2, 2, 128), 256, 0, stream>>>(A8, XST, OUTCAT);
  k_val16<<<dim3(1, 4, 512), 256, 0, stream>>>(A16, XST, OUTCAT);

  k_conv<0><<<dim3(128, 2, 2), 256, 0, stream>>>(OUTCAT, WTl, b_lin, nullptr,
                                                 (void*)FUSED, ZP, 256);
  k_conv<1><<<dim3(128, 4, 2), 256, 0, stream>>>(FUSED, WGF, b_gate, b_feat,
                                                 (void*)out, ZP, 512);
}

// Round 3
// 530.509 us; speedup vs baseline: 7.0451x; 1.0842x over previous
//
#include <hip/hip_runtime.h>

typedef unsigned short u16;
typedef unsigned int u32;
typedef __attribute__((ext_vector_type(8))) short bf16x8;   // 8 bf16 = 4 VGPR
typedef __attribute__((ext_vector_type(4))) float f32x4;

__device__ __forceinline__ float bf2f(u16 u){
  union { u32 i; float f; } v; v.i = ((u32)u) << 16; return v.f;
}
__device__ __forceinline__ u16 f2bf(float f){
  union { float f; u32 i; } v; v.f = f;
  u32 r = v.i + 0x7fffu + ((v.i >> 16) & 1u);
  return (u16)(r >> 16);
}
__device__ __forceinline__ void unpack8(uint4 v, float* dst){
  dst[0]=bf2f((u16)(v.x & 0xffff)); dst[1]=bf2f((u16)(v.x >> 16));
  dst[2]=bf2f((u16)(v.y & 0xffff)); dst[3]=bf2f((u16)(v.y >> 16));
  dst[4]=bf2f((u16)(v.z & 0xffff)); dst[5]=bf2f((u16)(v.z >> 16));
  dst[6]=bf2f((u16)(v.w & 0xffff)); dst[7]=bf2f((u16)(v.w >> 16));
}

// async global->LDS, 16B per lane; LDS dest = wave-uniform base + lane*16
__device__ __forceinline__ void gl16(const u16* g, u16* l){
  __builtin_amdgcn_global_load_lds(
      (const __attribute__((address_space(1))) u32*)g,
      (__attribute__((address_space(3))) u32*)l, 16, 0, 0);
}

// ---------------------------------------------------------------------------
__global__ __launch_bounds__(64) void k_zero(u32* zp){
  zp[threadIdx.x] = 0u;
}

// fp32 [rows][cols] -> bf16 [cols][rows(+ostride layout)] transpose per image z
__global__ __launch_bounds__(256) void k_transpose(const float* __restrict__ in,
                                                   u16* __restrict__ out,
                                                   int rows, int cols,
                                                   int ostride, size_t o_imgstride){
  __shared__ float s[32][33];
  const float* ip = in + (size_t)blockIdx.z * (size_t)rows * (size_t)cols;
  u16* op = out + (size_t)blockIdx.z * o_imgstride;
  int r0 = blockIdx.x * 32, c0 = blockIdx.y * 32;
  int tx = threadIdx.x, ty = threadIdx.y;
#pragma unroll
  for(int i = 0; i < 4; ++i){
    int r = ty * 4 + i;
    s[r][tx] = ip[(size_t)(r0 + r) * cols + (c0 + tx)];
  }
  __syncthreads();
#pragma unroll
  for(int i = 0; i < 4; ++i){
    int c = ty * 4 + i;
    op[(size_t)(c0 + c) * ostride + (r0 + tx)] = f2bf(s[tx][c]);
  }
}

// weights: [co][ci][3][3] f32 -> [e][co*co_mul+co_off][ci] bf16
__global__ __launch_bounds__(256) void k_wt(const float* __restrict__ in,
                                            u16* __restrict__ out,
                                            int co_mul, int co_off, int co_tot){
  int ci = blockIdx.x * 256 + threadIdx.x;   // 0..511
  int co = blockIdx.y;                       // 0..255
  int e  = blockIdx.z;                       // 0..8
  out[((size_t)e * co_tot + co * co_mul + co_off) * 512 + ci] =
      f2bf(in[((size_t)co * 512 + ci) * 9 + e]);
}

// ---------------------------------------------------------------------------
// scores8 MFMA: S8p[g][b][q=256][k=1280] partials, K-split over 8 tap-groups.
__global__ __launch_bounds__(256) void k_scores8(const u16* __restrict__ FUSED,
                                                 const u16* __restrict__ XST,
                                                 float* __restrict__ S8p){
  __shared__ u16 As[4096], Bs[4096];
  const int bz = blockIdx.z, b = bz >> 3, g = bz & 7;
  const int q0 = blockIdx.x * 128, k0 = blockIdx.y * 128;
  const int tid = threadIdx.x, w = tid >> 6, l = tid & 63;
  const int wr = w >> 1, wc = w & 1;
  const int l15 = l & 15, kg = (l >> 4) * 8;
  f32x4 acc[4][4];
#pragma unroll
  for(int m = 0; m < 4; ++m)
#pragma unroll
    for(int n = 0; n < 4; ++n) acc[m][n] = (f32x4){0.f, 0.f, 0.f, 0.f};

  for(int e8 = 0; e8 < 8; ++e8){
    const int e = g * 8 + e8, dy = e >> 3, dx = e & 7;
    for(int ci0 = 0; ci0 < 256; ci0 += 32){
#pragma unroll
      for(int r = 0; r < 2; ++r){
        const int idx = (w * 2 + r) * 64 + l;
        const int q = q0 + (idx >> 2);
        const size_t pa = ((size_t)b * 16384 +
                           (size_t)(((q >> 4) << 3) + dy) * 128 + ((q & 15) << 3) + dx) * 512
                          + ci0 + (idx & 3) * 8;
        gl16(FUSED + pa, As + (size_t)(w * 2 + r) * 512);
        const int k = k0 + (idx >> 2), t = k >> 8, rm = k & 255;
        const size_t pb = (((size_t)b * 5 + t) * 16384 +
                           (size_t)(((rm >> 4) << 3) + dy) * 128 + ((rm & 15) << 3) + dx) * 256
                          + ci0 + (idx & 3) * 8;
        gl16(XST + pb, Bs + (size_t)(w * 2 + r) * 512);
      }
      __syncthreads();
      bf16x8 af[4], bq[4];
#pragma unroll
      for(int m = 0; m < 4; ++m) af[m] = *(const bf16x8*)(As + (wr * 64 + m * 16 + l15) * 32 + kg);
#pragma unroll
      for(int n = 0; n < 4; ++n) bq[n] = *(const bf16x8*)(Bs + (wc * 64 + n * 16 + l15) * 32 + kg);
#pragma unroll
      for(int m = 0; m < 4; ++m)
#pragma unroll
        for(int n = 0; n < 4; ++n)
          acc[m][n] = __builtin_amdgcn_mfma_f32_16x16x32_bf16(af[m], bq[n], acc[m][n], 0, 0, 0);
      __syncthreads();
    }
  }
  float* dst = S8p + ((size_t)g * 2 + b) * 256 * 1280;
#pragma unroll
  for(int m = 0; m < 4; ++m){
    const int q = q0 + wr * 64 + m * 16 + (l >> 4) * 4;
#pragma unroll
    for(int n = 0; n < 4; ++n){
      const int k = k0 + wc * 64 + n * 16 + l15;
#pragma unroll
      for(int r = 0; r < 4; ++r) dst[(size_t)(q + r) * 1280 + k] = acc[m][n][r];
    }
  }
}

// softmax over k(1280), scale 1/128; sums 8 partials; writes A8 bf16.
__global__ __launch_bounds__(256) void k_softmax8(const float* __restrict__ S8p,
                                                  u16* __restrict__ A8){
  __shared__ float red[8];
  int b = blockIdx.x >> 8, q = blockIdx.x & 255;
  size_t roff = ((size_t)b * 256 + q) * 1280;
  int tid = threadIdx.x;
  float v[5]; float m = -1e30f;
#pragma unroll
  for(int i = 0; i < 5; ++i){
    size_t o = roff + tid + 256 * i;
    float s = 0.f;
#pragma unroll
    for(int g = 0; g < 8; ++g) s += S8p[(size_t)g * 655360 + o];
    v[i] = s * 0.0078125f; m = fmaxf(m, v[i]);
  }
#pragma unroll
  for(int o = 32; o > 0; o >>= 1) m = fmaxf(m, __shfl_xor(m, o));
  int wid = tid >> 6;
  if((tid & 63) == 0) red[wid] = m;
  __syncthreads();
  m = fmaxf(fmaxf(red[0], red[1]), fmaxf(red[2], red[3]));
  float s = 0.f;
#pragma unroll
  for(int i = 0; i < 5; ++i){ v[i] = __expf(v[i] - m); s += v[i]; }
#pragma unroll
  for(int o = 32; o > 0; o >>= 1) s += __shfl_xor(s, o);
  if((tid & 63) == 0) red[4 + wid] = s;
  __syncthreads();
  s = red[4] + red[5] + red[6] + red[7];
  float inv = 1.0f / s;
#pragma unroll
  for(int i = 0; i < 5; ++i) A8[roff + tid + 256 * i] = f2bf(v[i] * inv);
}

// scores16 from S8p quadrants, softmax over 320, scale 1/256 -> A16 f32.
__global__ __launch_bounds__(320) void k_s16(const float* __restrict__ S8p,
                                             float* __restrict__ A16){
  __shared__ float red[10];
  int b = blockIdx.x >> 6, q16 = blockIdx.x & 63;
  int tid = threadIdx.x;               // k16 in 0..319
  int t = tid >> 6, rm = tid & 63;
  int KY = rm >> 3, KX = rm & 7;
  int QY = q16 >> 3, QX = q16 & 7;
  float s = 0.f;
#pragma unroll
  for(int i = 0; i < 2; ++i)
#pragma unroll
    for(int j = 0; j < 2; ++j){
      int q8 = (2 * QY + i) * 16 + (2 * QX + j);
      int k8 = t * 256 + (2 * KY + i) * 16 + (2 * KX + j);
      size_t o = ((size_t)b * 256 + q8) * 1280 + k8;
#pragma unroll
      for(int g = 0; g < 8; ++g) s += S8p[(size_t)g * 655360 + o];
    }
  s *= 0.00390625f; // 1/256
  float m = s;
#pragma unroll
  for(int o = 32; o > 0; o >>= 1) m = fmaxf(m, __shfl_xor(m, o));
  int wid = tid >> 6;
  if((tid & 63) == 0) red[wid] = m;
  __syncthreads();
  m = fmaxf(fmaxf(fmaxf(red[0], red[1]), fmaxf(red[2], red[3])), red[4]);
  float e = __expf(s - m);
  float sm = e;
#pragma unroll
  for(int o = 32; o > 0; o >>= 1) sm += __shfl_xor(sm, o);
  if((tid & 63) == 0) red[5 + wid] = sm;
  __syncthreads();
  sm = red[5] + red[6] + red[7] + red[8] + red[9];
  A16[((size_t)b * 64 + q16) * 320 + tid] = e / sm;
}

// ---------------------------------------------------------------------------
// val8 MFMA: per (b,ry,rx): OUT[q=256][ch=256] = A8[q][1280] @ Gt[ch][1280].
// B staged via in-LDS transpose (NHWC [k][ch] -> LDS [ch][k], swizzled).
__global__ __launch_bounds__(256) void k_val8(const u16* __restrict__ A8,
                                              const u16* __restrict__ XST,
                                              u16* __restrict__ OUTCAT){
  __shared__ u16 As[4096];
  __shared__ u16 Bs[128 * 40];
  const int z = blockIdx.z, b = z >> 6, rr = z & 63;
  const int ry = rr >> 3, rx = rr & 7;
  const int q0 = blockIdx.x * 128, c0 = blockIdx.y * 128;
  const int tid = threadIdx.x, w = tid >> 6, l = tid & 63;
  const int wr = w >> 1, wc = w & 1;
  const int l15 = l & 15, kg = (l >> 4) * 8;
  const int k2 = tid >> 4, ch8 = tid & 15;   // B staging chunk
  f32x4 acc[4][4];
#pragma unroll
  for(int m = 0; m < 4; ++m)
#pragma unroll
    for(int n = 0; n < 4; ++n) acc[m][n] = (f32x4){0.f, 0.f, 0.f, 0.f};

  for(int k0 = 0; k0 < 1280; k0 += 32){
#pragma unroll
    for(int r = 0; r < 2; ++r){
      const int idx = (w * 2 + r) * 64 + l;
      const u16* ga = A8 + ((size_t)b * 256 + q0 + (idx >> 2)) * 1280 + k0 + (idx & 3) * 8;
      gl16(ga, As + (size_t)(w * 2 + r) * 512);
    }
    // B: rows k0+k2*2, k0+k2*2+1, channels c0 + ch8*8 .. +8
    {
      const int ka = k0 + k2 * 2, kb = ka + 1;
      const int ta = ka >> 8, ra = ka & 255;
      const int tb = kb >> 8, rb = kb & 255;
      const size_t pa = (((size_t)b * 5 + ta) * 16384 +
                         (size_t)(((ra >> 4) << 3) + ry) * 128 + ((ra & 15) << 3) + rx) * 256
                        + c0 + ch8 * 8;
      const size_t pb = (((size_t)b * 5 + tb) * 16384 +
                         (size_t)(((rb >> 4) << 3) + ry) * 128 + ((rb & 15) << 3) + rx) * 256
                        + c0 + ch8 * 8;
      union { uint4 v; u16 s[8]; } u0, u1;
      u0.v = *(const uint4*)(XST + pa);
      u1.v = *(const uint4*)(XST + pb);
      const int kloc = k2 * 2, swz = (ch8 & 3) << 3;
#pragma unroll
      for(int j = 0; j < 8; ++j){
        u32 pack = (u32)u0.s[j] | ((u32)u1.s[j] << 16);
        *(u32*)(Bs + (size_t)(ch8 * 8 + j) * 40 + (kloc ^ swz)) = pack;
      }
    }
    __syncthreads();
    bf16x8 af[4], bq[4];
#pragma unroll
    for(int m = 0; m < 4; ++m) af[m] = *(const bf16x8*)(As + (wr * 64 + m * 16 + l15) * 32 + kg);
#pragma unroll
    for(int n = 0; n < 4; ++n){
      const int ch = wc * 64 + n * 16 + l15;
      bq[n] = *(const bf16x8*)(Bs + (size_t)ch * 40 + (kg ^ (((ch >> 3) & 3) << 3)));
    }
#pragma unroll
    for(int m = 0; m < 4; ++m)
#pragma unroll
      for(int n = 0; n < 4; ++n)
        acc[m][n] = __builtin_amdgcn_mfma_f32_16x16x32_bf16(af[m], bq[n], acc[m][n], 0, 0, 0);
    __syncthreads();
  }
#pragma unroll
  for(int m = 0; m < 4; ++m){
    const int qb = q0 + wr * 64 + m * 16 + (l >> 4) * 4;
#pragma unroll
    for(int n = 0; n < 4; ++n){
      const int ch = c0 + wc * 64 + n * 16 + l15;
#pragma unroll
      for(int r = 0; r < 4; ++r){
        const int q = qb + r;
        const int py = ((q >> 4) << 3) + ry, px = ((q & 15) << 3) + rx;
        OUTCAT[((size_t)b * 16384 + (size_t)py * 128 + px) * 512 + ch] = f2bf(acc[m][n][r]);
      }
    }
  }
}

// val16 (fp32 path, small): OUT[q=64][ch=256] per (b,ry16,rx16) -> OUTCAT ch 256..511
__global__ __launch_bounds__(256) void k_val16(const float* __restrict__ A16,
                                               const u16* __restrict__ XST,
                                               u16* __restrict__ OUTCAT){
  __shared__ float As[64][68], Bs[64][68];
  int z = blockIdx.z; int b = z >> 8, rr = z & 255;
  int ry = rr >> 4, rx = rr & 15;
  int c0 = blockIdx.y * 64;
  int tid = threadIdx.x;
  int row = tid >> 2, quarter = tid & 3;
  int qg = tid >> 4, cg = tid & 15;
  float acc[4][4] = {{0.f}};
  for(int k0 = 0; k0 < 320; k0 += 64){
    {
      const float* src = A16 + ((size_t)b * 64 + row) * 320 + k0 + quarter * 16;
      float4 v0 = ((const float4*)src)[0];
      float4 v1 = ((const float4*)src)[1];
      float4 v2 = ((const float4*)src)[2];
      float4 v3 = ((const float4*)src)[3];
      float4* d = (float4*)&As[row][quarter * 16];
      d[0] = v0; d[1] = v1; d[2] = v2; d[3] = v3;
    }
    {
      int k = k0 + row;
      int t = k >> 6, rm = k & 63;
      int py = ((rm >> 3) << 4) + ry, px = ((rm & 7) << 4) + rx;
      const uint4* s4 = (const uint4*)(XST + ((((size_t)b * 5 + t) * 128 + py) * 128 + px) * 256 + c0 + quarter * 16);
      uint4 v0 = s4[0], v1 = s4[1];
      unpack8(v0, &Bs[row][quarter * 16]);
      unpack8(v1, &Bs[row][quarter * 16 + 8]);
    }
    __syncthreads();
#pragma unroll 8
    for(int kk = 0; kk < 64; ++kk){
      float a[4], bb[4];
#pragma unroll
      for(int i = 0; i < 4; ++i) a[i] = As[qg + 16 * i][kk];
#pragma unroll
      for(int j = 0; j < 4; ++j) bb[j] = Bs[kk][cg + 16 * j];
#pragma unroll
      for(int i = 0; i < 4; ++i)
#pragma unroll
        for(int j = 0; j < 4; ++j) acc[i][j] += a[i] * bb[j];
    }
    __syncthreads();
  }
#pragma unroll
  for(int i = 0; i < 4; ++i){
    int q = qg + 16 * i;
    int py = ((q >> 3) << 4) + ry, px = ((q & 7) << 4) + rx;
    u16* dst = OUTCAT + (((size_t)b * 128 + py) * 128 + px) * 512 + 256 + c0;
#pragma unroll
    for(int j = 0; j < 4; ++j) dst[cg + 16 * j] = f2bf(acc[i][j]);
  }
}

// ---------------------------------------------------------------------------
// Conv implicit-GEMM, 256^2-tile 8-wave schedule with counted vmcnt (T3/T4),
// T2 XOR-swizzled LDS, T5 setprio. BM=BN=256, BK=64, K = 9 taps x 512 ci.
// MODE 0: +bias, leaky, bf16 -> FUSED ch 256..511 (Ntot=256, 1 N-tile).
// MODE 1: interleaved gate/feat, sigmoid(g)*leaky(f) -> d_out NCHW f32.
template<int MODE>
__global__ __launch_bounds__(512, 2) void k_conv8(const u16* __restrict__ A,
                                                  const u16* __restrict__ W,
                                                  const float* __restrict__ bias,
                                                  const float* __restrict__ bias2,
                                                  void* __restrict__ outp,
                                                  const u16* __restrict__ zp,
                                                  int Ntot){
  // per buffer: A-tile [256 rows][64 k] bf16 @ 0, B-tile @ 16384 (u16 units)
  __shared__ u16 lds[2][32768];
  const int b = blockIdx.z;
  const int m0 = blockIdx.x * 256;          // pixel base (row-major p = py*128+px)
  const int n0 = blockIdx.y * 256;          // co base
  const int tid = threadIdx.x, w = tid >> 6, l = tid & 63;
  const int wr = w >> 2, wc = w & 3;        // 2 x 4 waves -> per-wave 128x64
  const int l15 = l & 15, lq = l >> 4;
  const int NT = 72;                        // 9 taps * (512/64)

  f32x4 acc[8][4];
#pragma unroll
  for(int m = 0; m < 8; ++m)
#pragma unroll
    for(int n = 0; n < 4; ++n) acc[m][n] = (f32x4){0.f, 0.f, 0.f, 0.f};

  // stage K-tile kt into buffer buf. Linear LDS dest; inverse-swizzled global src.
  auto STAGE = [&](int kt, int buf){
    const int e = kt >> 3, ci0 = (kt & 7) << 6;
    const int dy = e / 3 - 1, dx = e % 3 - 1;
    u16* bufA = &lds[buf][0];
    u16* bufB = &lds[buf][16384];
#pragma unroll
    for(int j = 0; j < 4; ++j){
      const int chunk = w * 4 + j;               // 32 chunks of 1 KiB
      const int row = chunk * 8 + (l >> 3);      // 0..255
      const int cb = (l & 7) * 16;               // byte col within 128B row
      const int obs = cb ^ ((row & 7) << 4);     // inverse swizzle (involution)
      {
        const int p = m0 + row;
        const int spy = (p >> 7) + dy, spx = (p & 127) + dx;
        const bool inb = ((unsigned)spy < 128u) && ((unsigned)spx < 128u);
        const u16* src = inb ? A + ((size_t)b * 16384 + spy * 128 + spx) * 512 + ci0 + (obs >> 1)
                             : zp;
        gl16(src, bufA + chunk * 512);
      }
      {
        const int co = n0 + row;
        const u16* src = W + ((size_t)e * Ntot + co) * 512 + ci0 + (obs >> 1);
        gl16(src, bufB + chunk * 512);
      }
    }
  };

  STAGE(0, 0);
  STAGE(1, 1);

  for(int t = 0; t < NT; ++t){
    const int cur = t & 1;
    if(t < NT - 1) asm volatile("s_waitcnt vmcnt(8)" ::: "memory");
    else           asm volatile("s_waitcnt vmcnt(0)" ::: "memory");
    asm volatile("s_barrier" ::: "memory");
    const char* bufA = (const char*)&lds[cur][0];
    const char* bufB = (const char*)&lds[cur][16384];
    bf16x8 af[8], bq[2];
#pragma unroll
    for(int s = 0; s < 2; ++s){
#pragma unroll
      for(int nh = 0; nh < 2; ++nh){
        if(nh == 0){
#pragma unroll
          for(int m = 0; m < 8; ++m){
            const int row = wr * 128 + m * 16 + l15;
            const int cb = ((s * 32 + lq * 8) << 1) ^ ((row & 7) << 4);
            af[m] = *(const bf16x8*)(bufA + row * 128 + cb);
          }
        }
#pragma unroll
        for(int nn = 0; nn < 2; ++nn){
          const int row = wc * 64 + (nh * 2 + nn) * 16 + l15;
          const int cb = ((s * 32 + lq * 8) << 1) ^ ((row & 7) << 4);
          bq[nn] = *(const bf16x8*)(bufB + row * 128 + cb);
        }
        __builtin_amdgcn_s_setprio(1);
#pragma unroll
        for(int m = 0; m < 8; ++m)
#pragma unroll
          for(int nn = 0; nn < 2; ++nn)
            acc[m][nh * 2 + nn] =
                __builtin_amdgcn_mfma_f32_16x16x32_bf16(af[m], bq[nn], acc[m][nh * 2 + nn], 0, 0, 0);
        __builtin_amdgcn_s_setprio(0);
        asm volatile("" ::: "memory");   // keep phase structure (no hoist/merge)
      }
    }
    asm volatile("s_barrier" ::: "memory");   // all reads of cur done
    if(t + 2 < NT) STAGE(t + 2, cur);         // refill just-freed buffer
  }

  if(MODE == 0){
    u16* ob = (u16*)outp;
#pragma unroll
    for(int m = 0; m < 8; ++m){
      const int p0 = m0 + wr * 128 + m * 16 + lq * 4;
#pragma unroll
      for(int n = 0; n < 4; ++n){
        const int co = n0 + wc * 64 + n * 16 + l15;
        const float bi = bias[co];
#pragma unroll
        for(int r = 0; r < 4; ++r){
          float v = acc[m][n][r] + bi;
          v = v > 0.f ? v : 0.2f * v;
          ob[((size_t)b * 16384 + p0 + r) * 512 + 256 + co] = f2bf(v);
        }
      }
    }
  } else {
    float* ob = (float*)outp;
#pragma unroll
    for(int m = 0; m < 8; ++m){
      const int p0 = m0 + wr * 128 + m * 16 + lq * 4;
#pragma unroll
      for(int n = 0; n < 4; ++n){
        const int col = n0 + wc * 64 + n * 16 + l15;
        const int s = col & 1, co = col >> 1;
        const float big = bias[co], bif = bias2[co];
        float res[4];
#pragma unroll
        for(int r = 0; r < 4; ++r){
          const float val = acc[m][n][r];
          const float oth = __shfl_xor(val, 1);
          float gg = s ? oth : val;
          float ff = s ? val : oth;
          gg += big; ff += bif;
          ff = ff > 0.f ? ff : 0.2f * ff;
          res[r] = ff / (1.0f + __expf(-gg));
        }
        if(s == 0){
          float4 v4 = make_float4(res[0], res[1], res[2], res[3]);
          *(float4*)&ob[((size_t)b * 256 + co) * 16384 + p0] = v4;
        }
      }
    }
  }
}

// ---------------------------------------------------------------------------
extern "C" void kernel_launch(void* const* d_in, const int* in_sizes, int n_in,
                              void* d_out, int out_size, void* d_ws, size_t ws_size,
                              hipStream_t stream){
  const float* x      = (const float*)d_in[0];
  const float* xs     = (const float*)d_in[1];
  // d_in[2] = ms : unused (mask is a no-op in the reference)
  const float* w_lin  = (const float*)d_in[3];
  const float* b_lin  = (const float*)d_in[4];
  const float* w_gate = (const float*)d_in[5];
  const float* b_gate = (const float*)d_in[6];
  const float* w_feat = (const float*)d_in[7];
  const float* b_feat = (const float*)d_in[8];
  float* out = (float*)d_out;

  char* ws = (char*)d_ws;
  size_t off = 0;
  auto alloc = [&](size_t bytes) -> void* {
    void* p = ws + off;
    off += (bytes + 255) & ~(size_t)255;
    return p;
  };
  u16* FUSED  = (u16*)alloc(2ull * 16384 * 512 * 2);  // [b][pix][512]: ch0-255=x, 256-511=lin
  u16* XST    = (u16*)alloc(10ull * 16384 * 256 * 2); // xs NHWC bf16
  u16* WTl    = (u16*)alloc(9ull * 256 * 512 * 2);    // [e][co][ci]
  u16* WGF    = (u16*)alloc(9ull * 512 * 512 * 2);    // [e][2co+s][ci]
  float* S8p  = (float*)alloc(8ull * 655360 * 4);     // [g][b][256][1280]
  u16* A8     = (u16*)alloc(655360ull * 2);           // bf16 [b][256][1280]
  float* A16  = (float*)alloc(2ull * 64 * 320 * 4);
  u16* OUTCAT = (u16*)alloc(2ull * 16384 * 512 * 2);  // [b][pix][512]
  u16* ZP     = (u16*)alloc(256);

  k_zero<<<1, 64, 0, stream>>>((u32*)ZP);

  dim3 tb(32, 8);
  k_transpose<<<dim3(8, 512, 2),  tb, 0, stream>>>(x,  FUSED, 256, 16384, 512, 8388608ull);
  k_transpose<<<dim3(8, 512, 10), tb, 0, stream>>>(xs, XST,   256, 16384, 256, 4194304ull);

  k_wt<<<dim3(2, 256, 9), 256, 0, stream>>>(w_lin,  WTl, 1, 0, 256);
  k_wt<<<dim3(2, 256, 9), 256, 0, stream>>>(w_gate, WGF, 2, 0, 512);
  k_wt<<<dim3(2, 256, 9), 256, 0, stream>>>(w_feat, WGF, 2, 1, 512);

  k_scores8<<<dim3(2, 10, 16), 256, 0, stream>>>(FUSED, XST, S8p);
  k_softmax8<<<512, 256, 0, stream>>>(S8p, A8);
  k_s16<<<128, 320, 0, stream>>>(S8p, A16);

  k_val8 <<<dim3(2, 2, 128), 256, 0, stream>>>(A8, XST, OUTCAT);
  k_val16<<<dim3(1, 4, 512), 256, 0, stream>>>(A16, XST, OUTCAT);

  k_conv8<0><<<dim3(64, 1, 2), 512, 0, stream>>>(OUTCAT, WTl, b_lin, nullptr,
                                                 (void*)FUSED, ZP, 256);
  k_conv8<1><<<dim3(64, 2, 2), 512, 0, stream>>>(FUSED, WGF, b_gate, b_feat,
                                                 (void*)out, ZP, 512);
}

// Round 4
// 483.068 us; speedup vs baseline: 7.7370x; 1.0982x over previous
//
#include <hip/hip_runtime.h>

typedef unsigned short u16;
typedef unsigned int u32;
typedef __attribute__((ext_vector_type(8))) short bf16x8;   // 8 bf16 = 4 VGPR
typedef __attribute__((ext_vector_type(4))) float f32x4;

#define MFMA16(d, a, bb) d = __builtin_amdgcn_mfma_f32_16x16x32_bf16(a, bb, d, 0, 0, 0)

__device__ __forceinline__ float bf2f(u16 u){
  union { u32 i; float f; } v; v.i = ((u32)u) << 16; return v.f;
}
__device__ __forceinline__ u16 f2bf(float f){
  union { float f; u32 i; } v; v.f = f;
  u32 r = v.i + 0x7fffu + ((v.i >> 16) & 1u);
  return (u16)(r >> 16);
}
__device__ __forceinline__ void unpack8(uint4 v, float* dst){
  dst[0]=bf2f((u16)(v.x & 0xffff)); dst[1]=bf2f((u16)(v.x >> 16));
  dst[2]=bf2f((u16)(v.y & 0xffff)); dst[3]=bf2f((u16)(v.y >> 16));
  dst[4]=bf2f((u16)(v.z & 0xffff)); dst[5]=bf2f((u16)(v.z >> 16));
  dst[6]=bf2f((u16)(v.w & 0xffff)); dst[7]=bf2f((u16)(v.w >> 16));
}

// async global->LDS, 16B per lane; LDS dest = wave-uniform base + lane*16
__device__ __forceinline__ void gl16(const u16* g, u16* l){
  __builtin_amdgcn_global_load_lds(
      (const __attribute__((address_space(1))) u32*)g,
      (__attribute__((address_space(3))) u32*)l, 16, 0, 0);
}

// ---------------------------------------------------------------------------
__global__ __launch_bounds__(64) void k_zero(u32* zp){
  zp[threadIdx.x] = 0u;
}

// fp32 [rows][cols] -> bf16 [cols][rows(+ostride layout)] transpose per image z
__global__ __launch_bounds__(256) void k_transpose(const float* __restrict__ in,
                                                   u16* __restrict__ out,
                                                   int rows, int cols,
                                                   int ostride, size_t o_imgstride){
  __shared__ float s[32][33];
  const float* ip = in + (size_t)blockIdx.z * (size_t)rows * (size_t)cols;
  u16* op = out + (size_t)blockIdx.z * o_imgstride;
  int r0 = blockIdx.x * 32, c0 = blockIdx.y * 32;
  int tx = threadIdx.x, ty = threadIdx.y;
#pragma unroll
  for(int i = 0; i < 4; ++i){
    int r = ty * 4 + i;
    s[r][tx] = ip[(size_t)(r0 + r) * cols + (c0 + tx)];
  }
  __syncthreads();
#pragma unroll
  for(int i = 0; i < 4; ++i){
    int c = ty * 4 + i;
    op[(size_t)(c0 + c) * ostride + (r0 + tx)] = f2bf(s[tx][c]);
  }
}

// weights: [co][ci][3][3] f32 -> [e][co*co_mul+co_off][ci] bf16
__global__ __launch_bounds__(256) void k_wt(const float* __restrict__ in,
                                            u16* __restrict__ out,
                                            int co_mul, int co_off, int co_tot){
  int ci = blockIdx.x * 256 + threadIdx.x;   // 0..511
  int co = blockIdx.y;                       // 0..255
  int e  = blockIdx.z;                       // 0..8
  out[((size_t)e * co_tot + co * co_mul + co_off) * 512 + ci] =
      f2bf(in[((size_t)co * 512 + ci) * 9 + e]);
}

// ---------------------------------------------------------------------------
// scores8 MFMA: S8p[g][b][q=256][k=1280] partials, K-split over 8 tap-groups.
__global__ __launch_bounds__(256) void k_scores8(const u16* __restrict__ FUSED,
                                                 const u16* __restrict__ XST,
                                                 float* __restrict__ S8p){
  __shared__ u16 As[4096], Bs[4096];
  const int bz = blockIdx.z, b = bz >> 3, g = bz & 7;
  const int q0 = blockIdx.x * 128, k0 = blockIdx.y * 128;
  const int tid = threadIdx.x, w = tid >> 6, l = tid & 63;
  const int wr = w >> 1, wc = w & 1;
  const int l15 = l & 15, kg = (l >> 4) * 8;
  f32x4 acc[4][4];
#pragma unroll
  for(int m = 0; m < 4; ++m)
#pragma unroll
    for(int n = 0; n < 4; ++n) acc[m][n] = (f32x4){0.f, 0.f, 0.f, 0.f};

  for(int e8 = 0; e8 < 8; ++e8){
    const int e = g * 8 + e8, dy = e >> 3, dx = e & 7;
    for(int ci0 = 0; ci0 < 256; ci0 += 32){
#pragma unroll
      for(int r = 0; r < 2; ++r){
        const int idx = (w * 2 + r) * 64 + l;
        const int q = q0 + (idx >> 2);
        const size_t pa = ((size_t)b * 16384 +
                           (size_t)(((q >> 4) << 3) + dy) * 128 + ((q & 15) << 3) + dx) * 512
                          + ci0 + (idx & 3) * 8;
        gl16(FUSED + pa, As + (size_t)(w * 2 + r) * 512);
        const int k = k0 + (idx >> 2), t = k >> 8, rm = k & 255;
        const size_t pb = (((size_t)b * 5 + t) * 16384 +
                           (size_t)(((rm >> 4) << 3) + dy) * 128 + ((rm & 15) << 3) + dx) * 256
                          + ci0 + (idx & 3) * 8;
        gl16(XST + pb, Bs + (size_t)(w * 2 + r) * 512);
      }
      __syncthreads();
      bf16x8 af[4], bq[4];
#pragma unroll
      for(int m = 0; m < 4; ++m) af[m] = *(const bf16x8*)(As + (wr * 64 + m * 16 + l15) * 32 + kg);
#pragma unroll
      for(int n = 0; n < 4; ++n) bq[n] = *(const bf16x8*)(Bs + (wc * 64 + n * 16 + l15) * 32 + kg);
#pragma unroll
      for(int m = 0; m < 4; ++m)
#pragma unroll
        for(int n = 0; n < 4; ++n)
          acc[m][n] = __builtin_amdgcn_mfma_f32_16x16x32_bf16(af[m], bq[n], acc[m][n], 0, 0, 0);
      __syncthreads();
    }
  }
  float* dst = S8p + ((size_t)g * 2 + b) * 256 * 1280;
#pragma unroll
  for(int m = 0; m < 4; ++m){
    const int q = q0 + wr * 64 + m * 16 + (l >> 4) * 4;
#pragma unroll
    for(int n = 0; n < 4; ++n){
      const int k = k0 + wc * 64 + n * 16 + l15;
#pragma unroll
      for(int r = 0; r < 4; ++r) dst[(size_t)(q + r) * 1280 + k] = acc[m][n][r];
    }
  }
}

// softmax over k(1280), scale 1/128; sums 8 partials; writes A8 bf16.
__global__ __launch_bounds__(256) void k_softmax8(const float* __restrict__ S8p,
                                                  u16* __restrict__ A8){
  __shared__ float red[8];
  int b = blockIdx.x >> 8, q = blockIdx.x & 255;
  size_t roff = ((size_t)b * 256 + q) * 1280;
  int tid = threadIdx.x;
  float v[5]; float m = -1e30f;
#pragma unroll
  for(int i = 0; i < 5; ++i){
    size_t o = roff + tid + 256 * i;
    float s = 0.f;
#pragma unroll
    for(int g = 0; g < 8; ++g) s += S8p[(size_t)g * 655360 + o];
    v[i] = s * 0.0078125f; m = fmaxf(m, v[i]);
  }
#pragma unroll
  for(int o = 32; o > 0; o >>= 1) m = fmaxf(m, __shfl_xor(m, o));
  int wid = tid >> 6;
  if((tid & 63) == 0) red[wid] = m;
  __syncthreads();
  m = fmaxf(fmaxf(red[0], red[1]), fmaxf(red[2], red[3]));
  float s = 0.f;
#pragma unroll
  for(int i = 0; i < 5; ++i){ v[i] = __expf(v[i] - m); s += v[i]; }
#pragma unroll
  for(int o = 32; o > 0; o >>= 1) s += __shfl_xor(s, o);
  if((tid & 63) == 0) red[4 + wid] = s;
  __syncthreads();
  s = red[4] + red[5] + red[6] + red[7];
  float inv = 1.0f / s;
#pragma unroll
  for(int i = 0; i < 5; ++i) A8[roff + tid + 256 * i] = f2bf(v[i] * inv);
}

// scores16 from S8p quadrants, softmax over 320, scale 1/256 -> A16 f32.
__global__ __launch_bounds__(320) void k_s16(const float* __restrict__ S8p,
                                             float* __restrict__ A16){
  __shared__ float red[10];
  int b = blockIdx.x >> 6, q16 = blockIdx.x & 63;
  int tid = threadIdx.x;               // k16 in 0..319
  int t = tid >> 6, rm = tid & 63;
  int KY = rm >> 3, KX = rm & 7;
  int QY = q16 >> 3, QX = q16 & 7;
  float s = 0.f;
#pragma unroll
  for(int i = 0; i < 2; ++i)
#pragma unroll
    for(int j = 0; j < 2; ++j){
      int q8 = (2 * QY + i) * 16 + (2 * QX + j);
      int k8 = t * 256 + (2 * KY + i) * 16 + (2 * KX + j);
      size_t o = ((size_t)b * 256 + q8) * 1280 + k8;
#pragma unroll
      for(int g = 0; g < 8; ++g) s += S8p[(size_t)g * 655360 + o];
    }
  s *= 0.00390625f; // 1/256
  float m = s;
#pragma unroll
  for(int o = 32; o > 0; o >>= 1) m = fmaxf(m, __shfl_xor(m, o));
  int wid = tid >> 6;
  if((tid & 63) == 0) red[wid] = m;
  __syncthreads();
  m = fmaxf(fmaxf(fmaxf(red[0], red[1]), fmaxf(red[2], red[3])), red[4]);
  float e = __expf(s - m);
  float sm = e;
#pragma unroll
  for(int o = 32; o > 0; o >>= 1) sm += __shfl_xor(sm, o);
  if((tid & 63) == 0) red[5 + wid] = sm;
  __syncthreads();
  sm = red[5] + red[6] + red[7] + red[8] + red[9];
  A16[((size_t)b * 64 + q16) * 320 + tid] = e / sm;
}

// ---------------------------------------------------------------------------
// val8 MFMA: per (b,ry,rx): OUT[q=256][ch=256] = A8[q][1280] @ Gt[ch][1280].
// B staged via in-LDS transpose (NHWC [k][ch] -> LDS [ch][k], swizzled).
__global__ __launch_bounds__(256) void k_val8(const u16* __restrict__ A8,
                                              const u16* __restrict__ XST,
                                              u16* __restrict__ OUTCAT){
  __shared__ u16 As[4096];
  __shared__ u16 Bs[128 * 40];
  const int z = blockIdx.z, b = z >> 6, rr = z & 63;
  const int ry = rr >> 3, rx = rr & 7;
  const int q0 = blockIdx.x * 128, c0 = blockIdx.y * 128;
  const int tid = threadIdx.x, w = tid >> 6, l = tid & 63;
  const int wr = w >> 1, wc = w & 1;
  const int l15 = l & 15, kg = (l >> 4) * 8;
  const int k2 = tid >> 4, ch8 = tid & 15;   // B staging chunk
  f32x4 acc[4][4];
#pragma unroll
  for(int m = 0; m < 4; ++m)
#pragma unroll
    for(int n = 0; n < 4; ++n) acc[m][n] = (f32x4){0.f, 0.f, 0.f, 0.f};

  for(int k0 = 0; k0 < 1280; k0 += 32){
#pragma unroll
    for(int r = 0; r < 2; ++r){
      const int idx = (w * 2 + r) * 64 + l;
      const u16* ga = A8 + ((size_t)b * 256 + q0 + (idx >> 2)) * 1280 + k0 + (idx & 3) * 8;
      gl16(ga, As + (size_t)(w * 2 + r) * 512);
    }
    // B: rows k0+k2*2, k0+k2*2+1, channels c0 + ch8*8 .. +8
    {
      const int ka = k0 + k2 * 2, kb = ka + 1;
      const int ta = ka >> 8, ra = ka & 255;
      const int tb = kb >> 8, rb = kb & 255;
      const size_t pa = (((size_t)b * 5 + ta) * 16384 +
                         (size_t)(((ra >> 4) << 3) + ry) * 128 + ((ra & 15) << 3) + rx) * 256
                        + c0 + ch8 * 8;
      const size_t pb = (((size_t)b * 5 + tb) * 16384 +
                         (size_t)(((rb >> 4) << 3) + ry) * 128 + ((rb & 15) << 3) + rx) * 256
                        + c0 + ch8 * 8;
      union { uint4 v; u16 s[8]; } u0, u1;
      u0.v = *(const uint4*)(XST + pa);
      u1.v = *(const uint4*)(XST + pb);
      const int kloc = k2 * 2, swz = (ch8 & 3) << 3;
#pragma unroll
      for(int j = 0; j < 8; ++j){
        u32 pack = (u32)u0.s[j] | ((u32)u1.s[j] << 16);
        *(u32*)(Bs + (size_t)(ch8 * 8 + j) * 40 + (kloc ^ swz)) = pack;
      }
    }
    __syncthreads();
    bf16x8 af[4], bq[4];
#pragma unroll
    for(int m = 0; m < 4; ++m) af[m] = *(const bf16x8*)(As + (wr * 64 + m * 16 + l15) * 32 + kg);
#pragma unroll
    for(int n = 0; n < 4; ++n){
      const int ch = wc * 64 + n * 16 + l15;
      bq[n] = *(const bf16x8*)(Bs + (size_t)ch * 40 + (kg ^ (((ch >> 3) & 3) << 3)));
    }
#pragma unroll
    for(int m = 0; m < 4; ++m)
#pragma unroll
      for(int n = 0; n < 4; ++n)
        acc[m][n] = __builtin_amdgcn_mfma_f32_16x16x32_bf16(af[m], bq[n], acc[m][n], 0, 0, 0);
    __syncthreads();
  }
#pragma unroll
  for(int m = 0; m < 4; ++m){
    const int qb = q0 + wr * 64 + m * 16 + (l >> 4) * 4;
#pragma unroll
    for(int n = 0; n < 4; ++n){
      const int ch = c0 + wc * 64 + n * 16 + l15;
#pragma unroll
      for(int r = 0; r < 4; ++r){
        const int q = qb + r;
        const int py = ((q >> 4) << 3) + ry, px = ((q & 15) << 3) + rx;
        OUTCAT[((size_t)b * 16384 + (size_t)py * 128 + px) * 512 + ch] = f2bf(acc[m][n][r]);
      }
    }
  }
}

// val16 (fp32 path, small): OUT[q=64][ch=256] per (b,ry16,rx16) -> OUTCAT ch 256..511
__global__ __launch_bounds__(256) void k_val16(const float* __restrict__ A16,
                                               const u16* __restrict__ XST,
                                               u16* __restrict__ OUTCAT){
  __shared__ float As[64][68], Bs[64][68];
  int z = blockIdx.z; int b = z >> 8, rr = z & 255;
  int ry = rr >> 4, rx = rr & 15;
  int c0 = blockIdx.y * 64;
  int tid = threadIdx.x;
  int row = tid >> 2, quarter = tid & 3;
  int qg = tid >> 4, cg = tid & 15;
  float acc[4][4] = {{0.f}};
  for(int k0 = 0; k0 < 320; k0 += 64){
    {
      const float* src = A16 + ((size_t)b * 64 + row) * 320 + k0 + quarter * 16;
      float4 v0 = ((const float4*)src)[0];
      float4 v1 = ((const float4*)src)[1];
      float4 v2 = ((const float4*)src)[2];
      float4 v3 = ((const float4*)src)[3];
      float4* d = (float4*)&As[row][quarter * 16];
      d[0] = v0; d[1] = v1; d[2] = v2; d[3] = v3;
    }
    {
      int k = k0 + row;
      int t = k >> 6, rm = k & 63;
      int py = ((rm >> 3) << 4) + ry, px = ((rm & 7) << 4) + rx;
      const uint4* s4 = (const uint4*)(XST + ((((size_t)b * 5 + t) * 128 + py) * 128 + px) * 256 + c0 + quarter * 16);
      uint4 v0 = s4[0], v1 = s4[1];
      unpack8(v0, &Bs[row][quarter * 16]);
      unpack8(v1, &Bs[row][quarter * 16 + 8]);
    }
    __syncthreads();
#pragma unroll 8
    for(int kk = 0; kk < 64; ++kk){
      float a[4], bb[4];
#pragma unroll
      for(int i = 0; i < 4; ++i) a[i] = As[qg + 16 * i][kk];
#pragma unroll
      for(int j = 0; j < 4; ++j) bb[j] = Bs[kk][cg + 16 * j];
#pragma unroll
      for(int i = 0; i < 4; ++i)
#pragma unroll
        for(int j = 0; j < 4; ++j) acc[i][j] += a[i] * bb[j];
    }
    __syncthreads();
  }
#pragma unroll
  for(int i = 0; i < 4; ++i){
    int q = qg + 16 * i;
    int py = ((q >> 3) << 4) + ry, px = ((q & 7) << 4) + rx;
    u16* dst = OUTCAT + (((size_t)b * 128 + py) * 128 + px) * 512 + 256 + c0;
#pragma unroll
    for(int j = 0; j < 4; ++j) dst[cg + 16 * j] = f2bf(acc[i][j]);
  }
}

// ---------------------------------------------------------------------------
// Conv implicit-GEMM, 8-phase schedule (T3+T4 counted vmcnt, T2 swizzle, T5
// setprio). Slot-granular double-buffer ring: per K-tile slots {A0,A1,B0,B1},
// staged one slot per phase; all bq read in phase 0 so B-slot overwrites are
// safe from phase 1 on; A-slot overwrites at ph3/ph0. vmcnt(6|5) once/tile.
// MODE 0: BM=128, +bias+leaky -> FUSED ch 256..511 (Ntot=256).
// MODE 1: BM=256, interleaved gate/feat -> sigmoid(g)*leaky(f) -> d_out f32.
template<int MODE>
__global__ __launch_bounds__(512, 2) void k_conv8(const u16* __restrict__ A,
                                                  const u16* __restrict__ W,
                                                  const float* __restrict__ bias,
                                                  const float* __restrict__ bias2,
                                                  void* __restrict__ outp,
                                                  const u16* __restrict__ zp,
                                                  int Ntot){
  constexpr int BM = (MODE == 0) ? 128 : 256;
  constexpr int MF = BM / 32;            // m-fragments per wave
  constexpr int AJ = BM / 128;           // gl16 per thread per A-slot
  constexpr int BUFU = (BM + 256) * 64;  // u16 per buffer (A then B, 64 u16/row)
  constexpr int NT = 72;                 // 9 taps * 8 ci-subtiles
  __shared__ u16 lds[2][BUFU];
  const int b = blockIdx.z;
  const int m0 = blockIdx.x * BM;
  const int n0 = blockIdx.y * 256;
  const int tid = threadIdx.x, w = tid >> 6, l = tid & 63;
  const int wr = w >> 2, wc = w & 3;     // 2 x 4 waves
  const int l15 = l & 15, lq = l >> 4;

  f32x4 acc[MF][4];
#pragma unroll
  for(int m = 0; m < MF; ++m)
#pragma unroll
    for(int n = 0; n < 4; ++n) acc[m][n] = (f32x4){0.f, 0.f, 0.f, 0.f};

  // stage A-slot (rows half*BM/2 .. +BM/2) of K-tile kt; linear LDS dest,
  // inverse-swizzled global source (round-3-verified addressing).
  auto STAGE_A = [&](int kt, int half){
    const int e = kt >> 3, ci0 = (kt & 7) << 6;
    const int dy = e / 3 - 1, dx = e % 3 - 1;
    u16* dstbase = &lds[kt & 1][0];
#pragma unroll
    for(int j = 0; j < AJ; ++j){
      const int chunk = w * AJ + j;
      const int rowc = half * (BM / 2) + chunk * 8;
      const int row = rowc + (l >> 3);
      const int obs = ((l & 7) * 16) ^ ((row & 7) << 4);
      const int p = m0 + row;
      const int spy = (p >> 7) + dy, spx = (p & 127) + dx;
      const bool inb = ((unsigned)spy < 128u) && ((unsigned)spx < 128u);
      const u16* src = inb ? A + ((size_t)b * 16384 + spy * 128 + spx) * 512 + ci0 + (obs >> 1)
                           : zp;
      gl16(src, dstbase + rowc * 64);
    }
  };
  auto STAGE_B = [&](int kt, int half){
    const int e = kt >> 3, ci0 = (kt & 7) << 6;
    u16* dstbase = &lds[kt & 1][BM * 64];
#pragma unroll
    for(int j = 0; j < 2; ++j){
      const int chunk = w * 2 + j;
      const int rowc = half * 128 + chunk * 8;
      const int row = rowc + (l >> 3);
      const int obs = ((l & 7) * 16) ^ ((row & 7) << 4);
      const int co = n0 + row;
      const u16* src = W + ((size_t)e * Ntot + co) * 512 + ci0 + (obs >> 1);
      gl16(src, dstbase + rowc * 64);
    }
  };

  // prologue: history = [B0(0),B1(0),A0(0),A1(0),B0(1),B1(1),A0(1)]
  STAGE_B(0, 0); STAGE_B(0, 1); STAGE_A(0, 0); STAGE_A(0, 1);
  STAGE_B(1, 0); STAGE_B(1, 1); STAGE_A(1, 0);
  if constexpr (MODE == 0) asm volatile("s_waitcnt vmcnt(5)" ::: "memory");
  else                     asm volatile("s_waitcnt vmcnt(6)" ::: "memory");
  __builtin_amdgcn_s_barrier();

  for(int t = 0; t < NT; ++t){
    const char* bufA = (const char*)&lds[t & 1][0];
    const char* bufB = bufA + BM * 128;
    bf16x8 af[MF], bq0[4], bq1[4];
    // ---- phase 0: read af(s0) + ALL bq; stage A1(t+1); MFMA (s0, n0/n1)
#pragma unroll
    for(int m = 0; m < MF; ++m){
      const int row = wr * (BM / 2) + m * 16 + l15;
      af[m] = *(const bf16x8*)(bufA + row * 128 + ((lq * 16) ^ ((row & 7) << 4)));
    }
#pragma unroll
    for(int n = 0; n < 4; ++n){
      const int row = wc * 64 + n * 16 + l15;
      const int sz = (row & 7) << 4;
      bq0[n] = *(const bf16x8*)(bufB + row * 128 + ((lq * 16) ^ sz));
      bq1[n] = *(const bf16x8*)(bufB + row * 128 + ((64 + lq * 16) ^ sz));
    }
    if(t + 1 < NT) STAGE_A(t + 1, 1);
    asm volatile("s_waitcnt lgkmcnt(0)" ::: "memory");
    __builtin_amdgcn_sched_barrier(0);
    __builtin_amdgcn_s_setprio(1);
#pragma unroll
    for(int m = 0; m < MF; ++m){
      MFMA16(acc[m][0], af[m], bq0[0]);
      MFMA16(acc[m][1], af[m], bq0[1]);
    }
    __builtin_amdgcn_s_setprio(0);
    __builtin_amdgcn_s_barrier();
    // ---- phase 1: stage B0(t+2); MFMA (s0, n2/n3)
    if(t + 2 < NT) STAGE_B(t + 2, 0);
    __builtin_amdgcn_s_setprio(1);
#pragma unroll
    for(int m = 0; m < MF; ++m){
      MFMA16(acc[m][2], af[m], bq0[2]);
      MFMA16(acc[m][3], af[m], bq0[3]);
    }
    __builtin_amdgcn_s_setprio(0);
    __builtin_amdgcn_s_barrier();
    // ---- phase 2: read af(s1); stage B1(t+2); MFMA (s1, n0/n1)
#pragma unroll
    for(int m = 0; m < MF; ++m){
      const int row = wr * (BM / 2) + m * 16 + l15;
      af[m] = *(const bf16x8*)(bufA + row * 128 + ((64 + lq * 16) ^ ((row & 7) << 4)));
    }
    if(t + 2 < NT) STAGE_B(t + 2, 1);
    asm volatile("s_waitcnt lgkmcnt(0)" ::: "memory");
    __builtin_amdgcn_sched_barrier(0);
    __builtin_amdgcn_s_setprio(1);
#pragma unroll
    for(int m = 0; m < MF; ++m){
      MFMA16(acc[m][0], af[m], bq1[0]);
      MFMA16(acc[m][1], af[m], bq1[1]);
    }
    __builtin_amdgcn_s_setprio(0);
    __builtin_amdgcn_s_barrier();
    // ---- phase 3: stage A0(t+2); MFMA (s1, n2/n3); vmcnt; tile barrier
    if(t + 2 < NT) STAGE_A(t + 2, 0);
    __builtin_amdgcn_s_setprio(1);
#pragma unroll
    for(int m = 0; m < MF; ++m){
      MFMA16(acc[m][2], af[m], bq1[2]);
      MFMA16(acc[m][3], af[m], bq1[3]);
    }
    __builtin_amdgcn_s_setprio(0);
    if(t < NT - 2){
      if constexpr (MODE == 0) asm volatile("s_waitcnt vmcnt(5)" ::: "memory");
      else                     asm volatile("s_waitcnt vmcnt(6)" ::: "memory");
    } else if(t == NT - 2){
      asm volatile("s_waitcnt vmcnt(0)" ::: "memory");
    }
    __builtin_amdgcn_s_barrier();
  }

  if(MODE == 0){
    u16* ob = (u16*)outp;
#pragma unroll
    for(int m = 0; m < MF; ++m){
      const int p0 = m0 + wr * (BM / 2) + m * 16 + lq * 4;
#pragma unroll
      for(int n = 0; n < 4; ++n){
        const int co = n0 + wc * 64 + n * 16 + l15;
        const float bi = bias[co];
#pragma unroll
        for(int r = 0; r < 4; ++r){
          float v = acc[m][n][r] + bi;
          v = v > 0.f ? v : 0.2f * v;
          ob[((size_t)b * 16384 + p0 + r) * 512 + 256 + co] = f2bf(v);
        }
      }
    }
  } else {
    float* ob = (float*)outp;
#pragma unroll
    for(int m = 0; m < MF; ++m){
      const int p0 = m0 + wr * (BM / 2) + m * 16 + lq * 4;
#pragma unroll
      for(int n = 0; n < 4; ++n){
        const int col = n0 + wc * 64 + n * 16 + l15;
        const int s = col & 1, co = col >> 1;
        const float big = bias[co], bif = bias2[co];
        float res[4];
#pragma unroll
        for(int r = 0; r < 4; ++r){
          const float val = acc[m][n][r];
          const float oth = __shfl_xor(val, 1);
          float gg = s ? oth : val;
          float ff = s ? val : oth;
          gg += big; ff += bif;
          ff = ff > 0.f ? ff : 0.2f * ff;
          res[r] = ff / (1.0f + __expf(-gg));
        }
        if(s == 0){
          float4 v4 = make_float4(res[0], res[1], res[2], res[3]);
          *(float4*)&ob[((size_t)b * 256 + co) * 16384 + p0] = v4;
        }
      }
    }
  }
}

// ---------------------------------------------------------------------------
extern "C" void kernel_launch(void* const* d_in, const int* in_sizes, int n_in,
                              void* d_out, int out_size, void* d_ws, size_t ws_size,
                              hipStream_t stream){
  const float* x      = (const float*)d_in[0];
  const float* xs     = (const float*)d_in[1];
  // d_in[2] = ms : unused (mask is a no-op in the reference)
  const float* w_lin  = (const float*)d_in[3];
  const float* b_lin  = (const float*)d_in[4];
  const float* w_gate = (const float*)d_in[5];
  const float* b_gate = (const float*)d_in[6];
  const float* w_feat = (const float*)d_in[7];
  const float* b_feat = (const float*)d_in[8];
  float* out = (float*)d_out;

  char* ws = (char*)d_ws;
  size_t off = 0;
  auto alloc = [&](size_t bytes) -> void* {
    void* p = ws + off;
    off += (bytes + 255) & ~(size_t)255;
    return p;
  };
  u16* FUSED  = (u16*)alloc(2ull * 16384 * 512 * 2);  // [b][pix][512]: ch0-255=x, 256-511=lin
  u16* XST    = (u16*)alloc(10ull * 16384 * 256 * 2); // xs NHWC bf16
  u16* WTl    = (u16*)alloc(9ull * 256 * 512 * 2);    // [e][co][ci]
  u16* WGF    = (u16*)alloc(9ull * 512 * 512 * 2);    // [e][2co+s][ci]
  float* S8p  = (float*)alloc(8ull * 655360 * 4);     // [g][b][256][1280]
  u16* A8     = (u16*)alloc(655360ull * 2);           // bf16 [b][256][1280]
  float* A16  = (float*)alloc(2ull * 64 * 320 * 4);
  u16* OUTCAT = (u16*)alloc(2ull * 16384 * 512 * 2);  // [b][pix][512]
  u16* ZP     = (u16*)alloc(256);

  k_zero<<<1, 64, 0, stream>>>((u32*)ZP);

  dim3 tb(32, 8);
  k_transpose<<<dim3(8, 512, 2),  tb, 0, stream>>>(x,  FUSED, 256, 16384, 512, 8388608ull);
  k_transpose<<<dim3(8, 512, 10), tb, 0, stream>>>(xs, XST,   256, 16384, 256, 4194304ull);

  k_wt<<<dim3(2, 256, 9), 256, 0, stream>>>(w_lin,  WTl, 1, 0, 256);
  k_wt<<<dim3(2, 256, 9), 256, 0, stream>>>(w_gate, WGF, 2, 0, 512);
  k_wt<<<dim3(2, 256, 9), 256, 0, stream>>>(w_feat, WGF, 2, 1, 512);

  k_scores8<<<dim3(2, 10, 16), 256, 0, stream>>>(FUSED, XST, S8p);
  k_softmax8<<<512, 256, 0, stream>>>(S8p, A8);
  k_s16<<<128, 320, 0, stream>>>(S8p, A16);

  k_val8 <<<dim3(2, 2, 128), 256, 0, stream>>>(A8, XST, OUTCAT);
  k_val16<<<dim3(1, 4, 512), 256, 0, stream>>>(A16, XST, OUTCAT);

  k_conv8<0><<<dim3(128, 1, 2), 512, 0, stream>>>(OUTCAT, WTl, b_lin, nullptr,
                                                  (void*)FUSED, ZP, 256);
  k_conv8<1><<<dim3(64, 2, 2), 512, 0, stream>>>(FUSED, WGF, b_gate, b_feat,
                                                 (void*)out, ZP, 512);
}